// Round 12
// baseline (482.565 us; speedup 1.0000x reference)
//
#include <hip/hip_runtime.h>

#define EPS  1e-5f
#define CNTF 409600.0f            // N*T*V
#define XDP_ELEMS 6553600         // per layer: 16384 nt * 400, layout [nt][u][16o]
#define ACC_ELEMS 26214400        // 16384 nt * 25 v * 64 ch (bf16)

typedef short bf16x8 __attribute__((ext_vector_type(8)));
typedef float f32x4  __attribute__((ext_vector_type(4)));

union FRAG { unsigned int u[4]; bf16x8 v; };

__device__ __forceinline__ float wave_sum(float v) {
#pragma unroll
    for (int off = 32; off > 0; off >>= 1)
        v += __shfl_down(v, off, 64);
    return v;
}

__device__ __forceinline__ float bfu(unsigned int u16) {
    union { unsigned int i; float f; } x;
    x.i = u16 << 16;
    return x.f;
}
__device__ __forceinline__ unsigned int f2bf(float f) {
    union { float f; unsigned int i; } u; u.f = f;
    unsigned int r = u.i + 0x7fff + ((u.i >> 16) & 1);
    return r >> 16;
}
__device__ __forceinline__ unsigned int packbf(float a, float b) {
    return f2bf(a) | (f2bf(b) << 16);
}

// register reshape: M-tile D-frag -> B2-frag via 2 packs + 4 shuffles.
__device__ __forceinline__ bf16x8 reshapeM(const f32x4 d, int sA, int sB) {
    unsigned int pk01 = packbf(d[0], d[1]);
    unsigned int pk23 = packbf(d[2], d[3]);
    FRAG f;
    f.u[0] = __shfl(pk01, sA, 64);
    f.u[1] = __shfl(pk23, sA, 64);
    f.u[2] = __shfl(pk01, sB, 64);
    f.u[3] = __shfl(pk23, sB, 64);
    return f.v;
}

// ---- K0: transpose W_down into [c][48] so k_down3 can scalar-load it
__global__ __launch_bounds__(256) void k_prep(const float* __restrict__ Wd,
                                              float* __restrict__ Wtg)
{
    for (int j = threadIdx.x; j < 3072; j += 256) {
        int c = j / 48, k = j - c * 48;
        int l = k / 16, o = k - l * 16;
        Wtg[j] = Wd[l * 1024 + o * 64 + c];
    }
}

// ---- K1: conv_down all 3 layers (bias cancels in BN), bf16 xd + stats.
__global__ __launch_bounds__(256) void k_down3(
    const float* __restrict__ x, const float* __restrict__ Wtg,
    unsigned short* __restrict__ xdp, float* __restrict__ st /*96*/)
{
    __shared__ float bins[96];
    const int tid = threadIdx.x;
    if (tid < 96) bins[tid] = 0.f;
    __syncthreads();

    const int base = (blockIdx.x * 256 + tid) * 2;
    const int n = base / 3200, pb = base - n * 3200;
    const float* xb = x + n * 204800 + pb;

    float acc0[48], acc1[48];
#pragma unroll
    for (int k = 0; k < 48; k++) { acc0[k] = 0.f; acc1[k] = 0.f; }

    for (int c = 0; c < 64; c++) {
        float2 xv = *(const float2*)&xb[c * 3200];
        const float4* wr = (const float4*)(Wtg + c * 48);   // uniform -> s_load
#pragma unroll
        for (int q = 0; q < 12; q++) {
            float4 w = wr[q];
            acc0[4*q+0] += w.x * xv.x;  acc1[4*q+0] += w.x * xv.y;
            acc0[4*q+1] += w.y * xv.x;  acc1[4*q+1] += w.y * xv.y;
            acc0[4*q+2] += w.z * xv.x;  acc1[4*q+2] += w.z * xv.y;
            acc0[4*q+3] += w.w * xv.x;  acc1[4*q+3] += w.w * xv.y;
        }
    }
#pragma unroll
    for (int l = 0; l < 3; l++) {
        unsigned int pk0[8], pk1[8];
#pragma unroll
        for (int h = 0; h < 8; h++) {
            pk0[h] = packbf(acc0[l*16 + 2*h], acc0[l*16 + 2*h + 1]);
            pk1[h] = packbf(acc1[l*16 + 2*h], acc1[l*16 + 2*h + 1]);
        }
        uint4* dst = (uint4*)(xdp + (size_t)l * XDP_ELEMS + (size_t)base * 16);
        dst[0] = make_uint4(pk0[0], pk0[1], pk0[2], pk0[3]);
        dst[1] = make_uint4(pk0[4], pk0[5], pk0[6], pk0[7]);
        dst[2] = make_uint4(pk1[0], pk1[1], pk1[2], pk1[3]);
        dst[3] = make_uint4(pk1[4], pk1[5], pk1[6], pk1[7]);
    }

    const int lane = tid & 63;
#pragma unroll
    for (int k = 0; k < 48; k++) {
        float sv = wave_sum(acc0[k] + acc1[k]);
        float qv = wave_sum(acc0[k] * acc0[k] + acc1[k] * acc1[k]);
        if (lane == 0) { atomicAdd(&bins[k], sv); atomicAdd(&bins[48 + k], qv); }
    }
    __syncthreads();
    if (tid < 96) atomicAdd(&st[tid], bins[tid]);
}

// ---- K2: finalize down affines
__global__ __launch_bounds__(64) void k_findown(
    const float* __restrict__ st, const float* __restrict__ gd,
    const float* __restrict__ betad, float* __restrict__ AC)
{
    int t = threadIdx.x;
    if (t < 48) {
        float m   = st[t] * (1.f / CNTF);
        float var = st[48 + t] * (1.f / CNTF) - m * m;
        float a   = gd[t] * rsqrtf(var + EPS);
        AC[t]      = a;
        AC[48 + t] = betad[t] - a * m;
    }
}

// ---- K3: per-layer z stats via MFMA (no z materialization).
__global__ __launch_bounds__(256, 1) void k_zstats(
    const unsigned short* __restrict__ xd,   // [nt][u<25][16c] bf16
    const float* __restrict__ PAl,           // [5][25][25]
    const float* __restrict__ Wsl,           // [80][16]
    const float* __restrict__ Al, const float* __restrict__ Cl,
    float* __restrict__ stql)                // [160]
{
    __shared__ unsigned short xtile[4][512];
    __shared__ float bins[160];

    const int tid  = threadIdx.x;
    const int wave = tid >> 6, lane = tid & 63;
    const int lr = lane & 15, lg = lane >> 4;
    const int q = lg & 1;
    const int sA = lr + 16 * (2 * q), sB = lr + 16 * (2 * q + 1);

    *(uint4*)&xtile[tid >> 6][(tid & 63) * 8] = make_uint4(0, 0, 0, 0);
    for (int i = tid; i < 160; i += 256) bins[i] = 0.f;
    __syncthreads();

    bf16x8 Bfrag[5][2];
#pragma unroll
    for (int s = 0; s < 5; s++)
#pragma unroll
        for (int t = 0; t < 2; t++) {
            FRAG f;
            const int v = t * 16 + lr;
#pragma unroll
            for (int h = 0; h < 4; h++) {
                int u0 = 8 * lg + 2 * h, u1 = u0 + 1;
                float f0 = (v < 25 && u0 < 25) ? PAl[(s * 25 + v) * 25 + u0] : 0.f;
                float f1 = (v < 25 && u1 < 25) ? PAl[(s * 25 + v) * 25 + u1] : 0.f;
                f.u[h] = packbf(f0, f1);
            }
            Bfrag[s][t] = f.v;
        }

    bf16x8 Wfrag[5];
#pragma unroll
    for (int s = 0; s < 5; s++) {
        FRAG f;
#pragma unroll
        for (int h = 0; h < 4; h++) {
            int c0 = 8 * lg + 2 * h, c1 = c0 + 1;
            float f0 = (c0 < 16) ? Wsl[(s * 16 + lr) * 16 + c0] : 0.f;
            float f1 = (c1 < 16) ? Wsl[(s * 16 + lr) * 16 + c1] : 0.f;
            f.u[h] = packbf(f0, f1);
        }
        Wfrag[s] = f.v;
    }

    const float a_c = Al[lr], c_c = Cl[lr];

    f32x4 sacc[5] = {};
    f32x4 qacc[5] = {};
    const f32x4 zero = {};

    const int wid = blockIdx.x * 4 + wave;
    for (int k = 0; k < 4; k++) {
        const int nt = wid * 4 + k;
        if (lane < 50)
            *(uint4*)&xtile[wave][lane * 8] =
                *(const uint4*)(xd + (size_t)nt * 400 + lane * 8);
        __syncthreads();

        FRAG af;
#pragma unroll
        for (int h = 0; h < 4; h++) {
            int u0 = 8 * lg + 2 * h;
            float x0 = bfu(xtile[wave][u0 * 16 + lr]);
            float x1 = bfu(xtile[wave][(u0 + 1) * 16 + lr]);
            x0 = fmaxf(a_c * x0 + c_c, 0.f);
            x1 = fmaxf(a_c * x1 + c_c, 0.f);
            af.u[h] = packbf(x0, x1);
        }
        const bf16x8 A = af.v;

#pragma unroll
        for (int s = 0; s < 5; s++) {
            f32x4 d0 = __builtin_amdgcn_mfma_f32_16x16x32_bf16(A, Bfrag[s][0], zero, 0, 0, 0);
            f32x4 d1 = __builtin_amdgcn_mfma_f32_16x16x32_bf16(A, Bfrag[s][1], zero, 0, 0, 0);
            bf16x8 b2a = reshapeM(d0, sA, sB);
            bf16x8 b2b = reshapeM(d1, sA, sB);
            f32x4 z0 = __builtin_amdgcn_mfma_f32_16x16x32_bf16(Wfrag[s], b2a, zero, 0, 0, 0);
            f32x4 z1 = __builtin_amdgcn_mfma_f32_16x16x32_bf16(Wfrag[s], b2b, zero, 0, 0, 0);
            sacc[s] += z0; qacc[s] += z0 * z0;
            if (lr < 9) { sacc[s] += z1; qacc[s] += z1 * z1; }
        }
        __syncthreads();   // compute done before next staging overwrites
    }

#pragma unroll
    for (int s = 0; s < 5; s++)
#pragma unroll
        for (int r = 0; r < 4; r++) {
            float sv = sacc[s][r], qv = qacc[s][r];
            sv += __shfl_xor(sv, 1, 64); qv += __shfl_xor(qv, 1, 64);
            sv += __shfl_xor(sv, 2, 64); qv += __shfl_xor(qv, 2, 64);
            sv += __shfl_xor(sv, 4, 64); qv += __shfl_xor(qv, 4, 64);
            sv += __shfl_xor(sv, 8, 64); qv += __shfl_xor(qv, 8, 64);
            if (lr == 0) {
                atomicAdd(&bins[s * 16 + 4 * lg + r], sv);
                atomicAdd(&bins[80 + s * 16 + 4 * lg + r], qv);
            }
        }
    __syncthreads();
    for (int i = tid; i < 160; i += 256) atomicAdd(&stql[i], bins[i]);
}

// ---- K4: fold sub-BN affine into W (W2 = A*W, bf16) and constants into Cagg[64]
__global__ __launch_bounds__(256) void k_finsub(
    const float* __restrict__ stq,    // [3][160]
    const float* __restrict__ Wsub,   // [3][80][16]
    const float* __restrict__ gs, const float* __restrict__ betas,
    unsigned short* __restrict__ W2,  // [3][80][16] bf16 (A-scaled)
    float* __restrict__ Cagg)         // [64]
{
    __shared__ float As[240], Cs[240];
    const int tid = threadIdx.x;
    if (tid < 240) {
        int l = tid / 80, ch = tid - l * 80;
        float m   = stq[l * 160 + ch] * (1.f / CNTF);
        float var = stq[l * 160 + 80 + ch] * (1.f / CNTF) - m * m;
        float a   = gs[l * 80 + ch] * rsqrtf(var + EPS);
        As[tid] = a;
        Cs[tid] = betas[l * 80 + ch] - a * m;
    }
    __syncthreads();
    for (int i = tid; i < 3840; i += 256) {
        int l = i / 1280, r = i - l * 1280, ch = r / 16;
        W2[i] = (unsigned short)f2bf(As[l * 80 + ch] * Wsub[i]);
    }
    if (tid < 64) {
        int sIdx = tid >> 4, o = tid & 15;
        float c = 0.f;
        for (int l = 0; l < 3; l++)
            c += Cs[l * 80 + (sIdx + 1) * 16 + o] + Cs[l * 80 + o];
        Cagg[tid] = c;
    }
}

// ---- K5: fused 3-layer output via MFMA -> bf16 acc [nt][v][64] + final-BN stats.
__global__ __launch_bounds__(256, 1) void k_out_mfma(
    const unsigned short* __restrict__ xdp,  // [3][nt][u<25][16c]
    const float* __restrict__ PA,            // [3][5][25][25]
    const unsigned short* __restrict__ W2,   // [3][80][16] bf16
    const float* __restrict__ Cagg,          // [64]
    const float* __restrict__ AC,            // [96] down affines
    float* __restrict__ stout,               // [128]
    unsigned short* __restrict__ accb)       // [nt][25][64] bf16
{
    __shared__ unsigned int PAfr[30 * 64 * 4];     // 30 frags x 64 lanes x uint4
    __shared__ unsigned short xtile[4][3][512];
    __shared__ float bins[128];

    const int tid  = threadIdx.x;
    const int wave = tid >> 6, lane = tid & 63;
    const int lr = lane & 15, lg = lane >> 4;
    const int q = lg & 1;
    const int sA = lr + 16 * (2 * q), sB = lr + 16 * (2 * q + 1);

    for (int e = tid; e < 1920; e += 256) {
        int frag = e >> 6, ln = e & 63;
        int l = frag / 10, rem = frag - l * 10;
        int s = rem >> 1, t = rem & 1;
        int elr = ln & 15, elg = ln >> 4;
        int v = t * 16 + elr;
        unsigned int u4[4];
#pragma unroll
        for (int h = 0; h < 4; h++) {
            int u0 = 8 * elg + 2 * h, u1 = u0 + 1;
            float f0 = (v < 25 && u0 < 25) ? PA[l * 3125 + (s * 25 + v) * 25 + u0] : 0.f;
            float f1 = (v < 25 && u1 < 25) ? PA[l * 3125 + (s * 25 + v) * 25 + u1] : 0.f;
            u4[h] = packbf(f0, f1);
        }
        *(uint4*)&PAfr[e * 4] = make_uint4(u4[0], u4[1], u4[2], u4[3]);
    }
    for (int i = tid; i < 768; i += 256)
        *(uint4*)&xtile[0][0][i * 8] = make_uint4(0, 0, 0, 0);
    if (tid < 128) bins[tid] = 0.f;

    bf16x8 Wf[3][5];
#pragma unroll
    for (int l = 0; l < 3; l++)
#pragma unroll
        for (int s = 0; s < 5; s++) {
            FRAG f;
            if (lg < 2)
                *(uint4*)f.u = *(const uint4*)(W2 + ((l * 5 + s) * 16 + lr) * 16 + lg * 8);
            else
                *(uint4*)f.u = make_uint4(0, 0, 0, 0);
            Wf[l][s] = f.v;
        }

    float a3[3], c3[3];
#pragma unroll
    for (int l = 0; l < 3; l++) { a3[l] = AC[l * 16 + lr]; c3[l] = AC[48 + l * 16 + lr]; }

    float cagg[4][4];
#pragma unroll
    for (int sI = 0; sI < 4; sI++)
#pragma unroll
        for (int r = 0; r < 4; r++) cagg[sI][r] = Cagg[sI * 16 + 4 * lg + r];

    f32x4 ss[4] = {}, qq[4] = {};
    const f32x4 zero = {};
    __syncthreads();   // PAfr ready

    const int wid = blockIdx.x * 4 + wave;
    for (int k = 0; k < 4; k++) {
        const int nt = wid * 4 + k;
#pragma unroll
        for (int it = 0; it < 3; it++) {
            int j = lane + it * 64;
            if (j < 150) {
                int l = j / 50, off = j - l * 50;
                *(uint4*)&xtile[wave][l][off * 8] =
                    *(const uint4*)(xdp + (size_t)l * XDP_ELEMS + (size_t)nt * 400 + off * 8);
            }
        }
        __syncthreads();

        f32x4 acc0[4] = {}, acc1[4] = {};
#pragma unroll
        for (int l = 0; l < 3; l++) {
            FRAG af;
#pragma unroll
            for (int h = 0; h < 4; h++) {
                int u0 = 8 * lg + 2 * h;
                float x0 = bfu(xtile[wave][l][u0 * 16 + lr]);
                float x1 = bfu(xtile[wave][l][(u0 + 1) * 16 + lr]);
                x0 = fmaxf(a3[l] * x0 + c3[l], 0.f);
                x1 = fmaxf(a3[l] * x1 + c3[l], 0.f);
                af.u[h] = packbf(x0, x1);
            }
            const bf16x8 A = af.v;

            f32x4 z0a, z0b;
#pragma unroll
            for (int s = 0; s < 5; s++) {
                FRAG bfA, bfB;
                *(uint4*)bfA.u = *(const uint4*)&PAfr[(((l * 5 + s) * 2 + 0) * 64 + lane) * 4];
                *(uint4*)bfB.u = *(const uint4*)&PAfr[(((l * 5 + s) * 2 + 1) * 64 + lane) * 4];
                f32x4 d0 = __builtin_amdgcn_mfma_f32_16x16x32_bf16(A, bfA.v, zero, 0, 0, 0);
                f32x4 d1 = __builtin_amdgcn_mfma_f32_16x16x32_bf16(A, bfB.v, zero, 0, 0, 0);
                bf16x8 b2a = reshapeM(d0, sA, sB);
                bf16x8 b2b = reshapeM(d1, sA, sB);
                f32x4 za = __builtin_amdgcn_mfma_f32_16x16x32_bf16(Wf[l][s], b2a, zero, 0, 0, 0);
                f32x4 zb = __builtin_amdgcn_mfma_f32_16x16x32_bf16(Wf[l][s], b2b, zero, 0, 0, 0);
                if (s == 0) { z0a = za; z0b = zb; }
                else {
                    acc0[s - 1] += za + z0a;
                    acc1[s - 1] += zb + z0b;
                }
            }
        }

        // bf16 acc write: [nt][v][64ch]; each (nt,v) row = 128B line.
        unsigned short* ab0 = accb + ((size_t)nt * 25 + lr) * 64;
        unsigned short* ab1 = accb + ((size_t)nt * 25 + 16 + lr) * 64;
#pragma unroll
        for (int sI = 0; sI < 4; sI++) {
            float v00 = acc0[sI][0] + cagg[sI][0];
            float v01 = acc0[sI][1] + cagg[sI][1];
            float v02 = acc0[sI][2] + cagg[sI][2];
            float v03 = acc0[sI][3] + cagg[sI][3];
            *(uint2*)(ab0 + sI * 16 + 4 * lg) =
                make_uint2(packbf(v00, v01), packbf(v02, v03));
            float v10 = acc1[sI][0] + cagg[sI][0];
            float v11 = acc1[sI][1] + cagg[sI][1];
            float v12 = acc1[sI][2] + cagg[sI][2];
            float v13 = acc1[sI][3] + cagg[sI][3];
            float u0 = (lr < 9) ? v10 : 0.f, u1 = (lr < 9) ? v11 : 0.f;
            float u2 = (lr < 9) ? v12 : 0.f, u3 = (lr < 9) ? v13 : 0.f;
            if (lr < 9)
                *(uint2*)(ab1 + sI * 16 + 4 * lg) =
                    make_uint2(packbf(v10, v11), packbf(v12, v13));
            ss[sI][0] += v00 + u0; qq[sI][0] += v00 * v00 + u0 * u0;
            ss[sI][1] += v01 + u1; qq[sI][1] += v01 * v01 + u1 * u1;
            ss[sI][2] += v02 + u2; qq[sI][2] += v02 * v02 + u2 * u2;
            ss[sI][3] += v03 + u3; qq[sI][3] += v03 * v03 + u3 * u3;
        }
        __syncthreads();   // all reads of xtile done before next staging
    }

#pragma unroll
    for (int sI = 0; sI < 4; sI++)
#pragma unroll
        for (int r = 0; r < 4; r++) {
            float sv = ss[sI][r], qv = qq[sI][r];
            sv += __shfl_xor(sv, 1, 64); qv += __shfl_xor(qv, 1, 64);
            sv += __shfl_xor(sv, 2, 64); qv += __shfl_xor(qv, 2, 64);
            sv += __shfl_xor(sv, 4, 64); qv += __shfl_xor(qv, 4, 64);
            sv += __shfl_xor(sv, 8, 64); qv += __shfl_xor(qv, 8, 64);
            if (lr == 0) {
                atomicAdd(&bins[sI * 16 + 4 * lg + r], sv);
                atomicAdd(&bins[64 + sI * 16 + 4 * lg + r], qv);
            }
        }
    __syncthreads();
    if (tid < 128) atomicAdd(&stout[tid], bins[tid]);
}

// ---- K6: out = relu(bn(acc) + x), coalesced via LDS transpose (8 nt/block)
__global__ __launch_bounds__(256, 2) void k_final2(
    const unsigned short* __restrict__ accb, const float* __restrict__ x,
    const float* __restrict__ go, const float* __restrict__ bo,
    const float* __restrict__ stout, float* __restrict__ out)
{
    __shared__ float ao[64], co[64];
    __shared__ float tile[32][208];
    const int tid = threadIdx.x;
    if (tid < 64) {
        float m   = stout[tid] * (1.f / CNTF);
        float var = stout[64 + tid] * (1.f / CNTF) - m * m;
        float a   = go[tid] * rsqrtf(var + EPS);
        ao[tid] = a; co[tid] = bo[tid] - m * a;
    }

    const int nt0 = blockIdx.x * 8, n = nt0 >> 7, t0 = nt0 & 127;
    const int pp = tid / 25, v = tid - pp * 25;
    const unsigned short* arow = accb + ((size_t)(nt0 + pp) * 25 + v) * 64;

#pragma unroll
    for (int h = 0; h < 2; h++) {
        __syncthreads();   // ao/co ready (h=0) / prev-half tile reads done (h=1)
        if (tid < 200) {
#pragma unroll
            for (int j = 0; j < 4; j++) {
                uint4 w = *(const uint4*)(arow + h * 32 + j * 8);
                const int cb = h * 32 + j * 8;
                tile[j*8+0][tid] = ao[cb+0] * bfu(w.x & 0xffffu) + co[cb+0];
                tile[j*8+1][tid] = ao[cb+1] * bfu(w.x >> 16)     + co[cb+1];
                tile[j*8+2][tid] = ao[cb+2] * bfu(w.y & 0xffffu) + co[cb+2];
                tile[j*8+3][tid] = ao[cb+3] * bfu(w.y >> 16)     + co[cb+3];
                tile[j*8+4][tid] = ao[cb+4] * bfu(w.z & 0xffffu) + co[cb+4];
                tile[j*8+5][tid] = ao[cb+5] * bfu(w.z >> 16)     + co[cb+5];
                tile[j*8+6][tid] = ao[cb+6] * bfu(w.w & 0xffffu) + co[cb+6];
                tile[j*8+7][tid] = ao[cb+7] * bfu(w.w >> 16)     + co[cb+7];
            }
        }
        __syncthreads();
        for (int i = tid; i < 6400; i += 256) {
            int kk = i / 200, p = i - kk * 200;
            int adr = n * 204800 + (h * 32 + kk) * 3200 + t0 * 25 + p;
            out[adr] = fmaxf(tile[kk][p] + x[adr], 0.f);
        }
    }
}

extern "C" void kernel_launch(void* const* d_in, const int* in_sizes, int n_in,
                              void* d_out, int out_size, void* d_ws, size_t ws_size,
                              hipStream_t stream)
{
    const float* x     = (const float*)d_in[0];
    const float* PA    = (const float*)d_in[1];
    const float* Wd    = (const float*)d_in[2];
    const float* gd    = (const float*)d_in[4];
    const float* betad = (const float*)d_in[5];
    const float* Wsub  = (const float*)d_in[6];
    const float* gsub  = (const float*)d_in[8];
    const float* betas = (const float*)d_in[9];
    const float* gout  = (const float*)d_in[10];
    const float* betao = (const float*)d_in[11];
    float* out = (float*)d_out;

    unsigned short* xdp  = (unsigned short*)d_ws;            // 39.3 MB
    unsigned short* accb = xdp + (size_t)3 * XDP_ELEMS;      // 52.4 MB bf16
    float* st    = (float*)(accb + (size_t)ACC_ELEMS);
    float* AC    = st + 96;
    float* stq   = AC + 96;       // [3][160]
    float* stout = stq + 480;     // [128]
    float* Wtg   = stout + 128;   // [64][48]
    float* Cagg  = Wtg + 3072;    // [64]
    unsigned short* W2 = (unsigned short*)(Cagg + 64);  // [3][80][16] bf16

    hipMemsetAsync(st, 0, (96 + 96 + 480 + 128) * sizeof(float), stream);

    k_prep   <<<1,   256, 0, stream>>>(Wd, Wtg);
    k_down3  <<<800, 256, 0, stream>>>(x, Wtg, xdp, st);
    k_findown<<<1,    64, 0, stream>>>(st, gd, betad, AC);

    for (int l = 0; l < 3; l++)
        k_zstats<<<1024, 256, 0, stream>>>(xdp + (size_t)l * XDP_ELEMS, PA + l * 3125,
                                           Wsub + l * 1280, AC + l * 16, AC + 48 + l * 16,
                                           stq + l * 160);
    k_finsub  <<<1,    256, 0, stream>>>(stq, Wsub, gsub, betas, W2, Cagg);
    k_out_mfma<<<1024, 256, 0, stream>>>(xdp, PA, W2, Cagg, AC, stout, accb);
    k_final2  <<<2048, 256, 0, stream>>>(accb, x, gout, betao, stout, out);
}

// Round 13
// 467.110 us; speedup vs baseline: 1.0331x; 1.0331x over previous
//
#include <hip/hip_runtime.h>

#define EPS  1e-5f
#define CNTF 409600.0f            // N*T*V
#define XDP_ELEMS 6553600         // per layer: 16384 nt * 400, layout [nt][u][16o]
#define ACC_ELEMS 26214400        // 16384 nt * 25 v * 64 ch (bf16)

typedef short bf16x8 __attribute__((ext_vector_type(8)));
typedef float f32x4  __attribute__((ext_vector_type(4)));

union FRAG { unsigned int u[4]; bf16x8 v; };

__device__ __forceinline__ float wave_sum(float v) {
#pragma unroll
    for (int off = 32; off > 0; off >>= 1)
        v += __shfl_down(v, off, 64);
    return v;
}

__device__ __forceinline__ float bfu(unsigned int u16) {
    union { unsigned int i; float f; } x;
    x.i = u16 << 16;
    return x.f;
}
__device__ __forceinline__ unsigned int f2bf(float f) {
    union { float f; unsigned int i; } u; u.f = f;
    unsigned int r = u.i + 0x7fff + ((u.i >> 16) & 1);
    return r >> 16;
}
__device__ __forceinline__ unsigned int packbf(float a, float b) {
    return f2bf(a) | (f2bf(b) << 16);
}

// register reshape: M-tile D-frag -> B2-frag via 2 packs + 4 shuffles.
__device__ __forceinline__ bf16x8 reshapeM(const f32x4 d, int sA, int sB) {
    unsigned int pk01 = packbf(d[0], d[1]);
    unsigned int pk23 = packbf(d[2], d[3]);
    FRAG f;
    f.u[0] = __shfl(pk01, sA, 64);
    f.u[1] = __shfl(pk23, sA, 64);
    f.u[2] = __shfl(pk01, sB, 64);
    f.u[3] = __shfl(pk23, sB, 64);
    return f.v;
}

// ---- K0: transpose W_down into [c][48] so k_down3 can scalar-load it
__global__ __launch_bounds__(256) void k_prep(const float* __restrict__ Wd,
                                              float* __restrict__ Wtg)
{
    for (int j = threadIdx.x; j < 3072; j += 256) {
        int c = j / 48, k = j - c * 48;
        int l = k / 16, o = k - l * 16;
        Wtg[j] = Wd[l * 1024 + o * 64 + c];
    }
}

// ---- K1: conv_down all 3 layers (bias cancels in BN), bf16 xd + stats.
__global__ __launch_bounds__(256) void k_down3(
    const float* __restrict__ x, const float* __restrict__ Wtg,
    unsigned short* __restrict__ xdp, float* __restrict__ st /*96*/)
{
    __shared__ float bins[96];
    const int tid = threadIdx.x;
    if (tid < 96) bins[tid] = 0.f;
    __syncthreads();

    const int base = (blockIdx.x * 256 + tid) * 2;
    const int n = base / 3200, pb = base - n * 3200;
    const float* xb = x + n * 204800 + pb;

    float acc0[48], acc1[48];
#pragma unroll
    for (int k = 0; k < 48; k++) { acc0[k] = 0.f; acc1[k] = 0.f; }

    for (int c = 0; c < 64; c++) {
        float2 xv = *(const float2*)&xb[c * 3200];
        const float4* wr = (const float4*)(Wtg + c * 48);   // uniform -> s_load
#pragma unroll
        for (int q = 0; q < 12; q++) {
            float4 w = wr[q];
            acc0[4*q+0] += w.x * xv.x;  acc1[4*q+0] += w.x * xv.y;
            acc0[4*q+1] += w.y * xv.x;  acc1[4*q+1] += w.y * xv.y;
            acc0[4*q+2] += w.z * xv.x;  acc1[4*q+2] += w.z * xv.y;
            acc0[4*q+3] += w.w * xv.x;  acc1[4*q+3] += w.w * xv.y;
        }
    }
#pragma unroll
    for (int l = 0; l < 3; l++) {
        unsigned int pk0[8], pk1[8];
#pragma unroll
        for (int h = 0; h < 8; h++) {
            pk0[h] = packbf(acc0[l*16 + 2*h], acc0[l*16 + 2*h + 1]);
            pk1[h] = packbf(acc1[l*16 + 2*h], acc1[l*16 + 2*h + 1]);
        }
        uint4* dst = (uint4*)(xdp + (size_t)l * XDP_ELEMS + (size_t)base * 16);
        dst[0] = make_uint4(pk0[0], pk0[1], pk0[2], pk0[3]);
        dst[1] = make_uint4(pk0[4], pk0[5], pk0[6], pk0[7]);
        dst[2] = make_uint4(pk1[0], pk1[1], pk1[2], pk1[3]);
        dst[3] = make_uint4(pk1[4], pk1[5], pk1[6], pk1[7]);
    }

    const int lane = tid & 63;
#pragma unroll
    for (int k = 0; k < 48; k++) {
        float sv = wave_sum(acc0[k] + acc1[k]);
        float qv = wave_sum(acc0[k] * acc0[k] + acc1[k] * acc1[k]);
        if (lane == 0) { atomicAdd(&bins[k], sv); atomicAdd(&bins[48 + k], qv); }
    }
    __syncthreads();
    if (tid < 96) atomicAdd(&st[tid], bins[tid]);
}

// ---- K2: finalize down affines
__global__ __launch_bounds__(64) void k_findown(
    const float* __restrict__ st, const float* __restrict__ gd,
    const float* __restrict__ betad, float* __restrict__ AC)
{
    int t = threadIdx.x;
    if (t < 48) {
        float m   = st[t] * (1.f / CNTF);
        float var = st[48 + t] * (1.f / CNTF) - m * m;
        float a   = gd[t] * rsqrtf(var + EPS);
        AC[t]      = a;
        AC[48 + t] = betad[t] - a * m;
    }
}

// ---- K3: per-layer z stats via MFMA (no z materialization).
// k-slot map u(lg, 2h)=8h+lg, u(lg,2h+1)=8h+4+lg -> A-reads conflict-free
// (banks 8*lg + lr/2: disjoint per lg group). xtile wave-private: no barriers
// in the nt loop, just lgkmcnt after staging.
__global__ __launch_bounds__(256, 1) void k_zstats(
    const unsigned short* __restrict__ xd,   // [nt][u<25][16c] bf16
    const float* __restrict__ PAl,           // [5][25][25]
    const float* __restrict__ Wsl,           // [80][16]
    const float* __restrict__ Al, const float* __restrict__ Cl,
    float* __restrict__ stql)                // [160]
{
    __shared__ unsigned short xtile[4][512];
    __shared__ float bins[160];

    const int tid  = threadIdx.x;
    const int wave = tid >> 6, lane = tid & 63;
    const int lr = lane & 15, lg = lane >> 4;
    const int q = lg & 1;
    const int sA = lr + 16 * (2 * q), sB = lr + 16 * (2 * q + 1);

    *(uint4*)&xtile[tid >> 6][(tid & 63) * 8] = make_uint4(0, 0, 0, 0);
    for (int i = tid; i < 160; i += 256) bins[i] = 0.f;
    __syncthreads();

    bf16x8 Bfrag[5][2];
#pragma unroll
    for (int s = 0; s < 5; s++)
#pragma unroll
        for (int t = 0; t < 2; t++) {
            FRAG f;
            const int v = t * 16 + lr;
#pragma unroll
            for (int h = 0; h < 4; h++) {
                int u0 = 8 * h + lg, u1 = 8 * h + 4 + lg;
                float f0 = (v < 25 && u0 < 25) ? PAl[(s * 25 + v) * 25 + u0] : 0.f;
                float f1 = (v < 25 && u1 < 25) ? PAl[(s * 25 + v) * 25 + u1] : 0.f;
                f.u[h] = packbf(f0, f1);
            }
            Bfrag[s][t] = f.v;
        }

    bf16x8 Wfrag[5];
#pragma unroll
    for (int s = 0; s < 5; s++) {
        FRAG f;
#pragma unroll
        for (int h = 0; h < 4; h++) {
            int c0 = 8 * lg + 2 * h, c1 = c0 + 1;
            float f0 = (c0 < 16) ? Wsl[(s * 16 + lr) * 16 + c0] : 0.f;
            float f1 = (c1 < 16) ? Wsl[(s * 16 + lr) * 16 + c1] : 0.f;
            f.u[h] = packbf(f0, f1);
        }
        Wfrag[s] = f.v;
    }

    const float a_c = Al[lr], c_c = Cl[lr];

    f32x4 sacc[5] = {};
    f32x4 qacc[5] = {};
    const f32x4 zero = {};

    const int wid = blockIdx.x * 4 + wave;
    for (int k = 0; k < 4; k++) {
        const int nt = wid * 4 + k;
        if (lane < 50)
            *(uint4*)&xtile[wave][lane * 8] =
                *(const uint4*)(xd + (size_t)nt * 400 + lane * 8);
        asm volatile("s_waitcnt lgkmcnt(0)" ::: "memory");
        __builtin_amdgcn_sched_barrier(0);

        FRAG af;
#pragma unroll
        for (int h = 0; h < 4; h++) {
            int u0 = 8 * h + lg, u1 = 8 * h + 4 + lg;
            float x0 = bfu(xtile[wave][u0 * 16 + lr]);
            float x1 = bfu(xtile[wave][u1 * 16 + lr]);
            x0 = fmaxf(a_c * x0 + c_c, 0.f);
            x1 = fmaxf(a_c * x1 + c_c, 0.f);
            af.u[h] = packbf(x0, x1);
        }
        const bf16x8 A = af.v;

#pragma unroll
        for (int s = 0; s < 5; s++) {
            f32x4 d0 = __builtin_amdgcn_mfma_f32_16x16x32_bf16(A, Bfrag[s][0], zero, 0, 0, 0);
            f32x4 d1 = __builtin_amdgcn_mfma_f32_16x16x32_bf16(A, Bfrag[s][1], zero, 0, 0, 0);
            bf16x8 b2a = reshapeM(d0, sA, sB);
            bf16x8 b2b = reshapeM(d1, sA, sB);
            f32x4 z0 = __builtin_amdgcn_mfma_f32_16x16x32_bf16(Wfrag[s], b2a, zero, 0, 0, 0);
            f32x4 z1 = __builtin_amdgcn_mfma_f32_16x16x32_bf16(Wfrag[s], b2b, zero, 0, 0, 0);
            sacc[s] += z0; qacc[s] += z0 * z0;
            if (lr < 9) { sacc[s] += z1; qacc[s] += z1 * z1; }
        }
    }

#pragma unroll
    for (int s = 0; s < 5; s++)
#pragma unroll
        for (int r = 0; r < 4; r++) {
            float sv = sacc[s][r], qv = qacc[s][r];
            sv += __shfl_xor(sv, 1, 64); qv += __shfl_xor(qv, 1, 64);
            sv += __shfl_xor(sv, 2, 64); qv += __shfl_xor(qv, 2, 64);
            sv += __shfl_xor(sv, 4, 64); qv += __shfl_xor(qv, 4, 64);
            sv += __shfl_xor(sv, 8, 64); qv += __shfl_xor(qv, 8, 64);
            if (lr == 0) {
                atomicAdd(&bins[s * 16 + 4 * lg + r], sv);
                atomicAdd(&bins[80 + s * 16 + 4 * lg + r], qv);
            }
        }
    __syncthreads();
    for (int i = tid; i < 160; i += 256) atomicAdd(&stql[i], bins[i]);
}

// ---- K4: fold sub-BN affine into W (W2 = A*W, bf16) and constants into Cagg[64]
__global__ __launch_bounds__(256) void k_finsub(
    const float* __restrict__ stq,    // [3][160]
    const float* __restrict__ Wsub,   // [3][80][16]
    const float* __restrict__ gs, const float* __restrict__ betas,
    unsigned short* __restrict__ W2,  // [3][80][16] bf16 (A-scaled)
    float* __restrict__ Cagg)         // [64]
{
    __shared__ float As[240], Cs[240];
    const int tid = threadIdx.x;
    if (tid < 240) {
        int l = tid / 80, ch = tid - l * 80;
        float m   = stq[l * 160 + ch] * (1.f / CNTF);
        float var = stq[l * 160 + 80 + ch] * (1.f / CNTF) - m * m;
        float a   = gs[l * 80 + ch] * rsqrtf(var + EPS);
        As[tid] = a;
        Cs[tid] = betas[l * 80 + ch] - a * m;
    }
    __syncthreads();
    for (int i = tid; i < 3840; i += 256) {
        int l = i / 1280, r = i - l * 1280, ch = r / 16;
        W2[i] = (unsigned short)f2bf(As[l * 80 + ch] * Wsub[i]);
    }
    if (tid < 64) {
        int sIdx = tid >> 4, o = tid & 15;
        float c = 0.f;
        for (int l = 0; l < 3; l++)
            c += Cs[l * 80 + (sIdx + 1) * 16 + o] + Cs[l * 80 + o];
        Cagg[tid] = c;
    }
}

// ---- K5: fused 3-layer output via MFMA -> bf16 acc [nt][v][64] + final-BN stats.
__global__ __launch_bounds__(256, 1) void k_out_mfma(
    const unsigned short* __restrict__ xdp,  // [3][nt][u<25][16c]
    const float* __restrict__ PA,            // [3][5][25][25]
    const unsigned short* __restrict__ W2,   // [3][80][16] bf16
    const float* __restrict__ Cagg,          // [64]
    const float* __restrict__ AC,            // [96] down affines
    float* __restrict__ stout,               // [128]
    unsigned short* __restrict__ accb)       // [nt][25][64] bf16
{
    __shared__ unsigned int PAfr[30 * 64 * 4];     // 30 frags x 64 lanes x uint4
    __shared__ unsigned short xtile[4][3][512];
    __shared__ float bins[128];

    const int tid  = threadIdx.x;
    const int wave = tid >> 6, lane = tid & 63;
    const int lr = lane & 15, lg = lane >> 4;
    const int q = lg & 1;
    const int sA = lr + 16 * (2 * q), sB = lr + 16 * (2 * q + 1);

    for (int e = tid; e < 1920; e += 256) {
        int frag = e >> 6, ln = e & 63;
        int l = frag / 10, rem = frag - l * 10;
        int s = rem >> 1, t = rem & 1;
        int elr = ln & 15, elg = ln >> 4;
        int v = t * 16 + elr;
        unsigned int u4[4];
#pragma unroll
        for (int h = 0; h < 4; h++) {
            int u0 = 8 * h + elg, u1 = 8 * h + 4 + elg;
            float f0 = (v < 25 && u0 < 25) ? PA[l * 3125 + (s * 25 + v) * 25 + u0] : 0.f;
            float f1 = (v < 25 && u1 < 25) ? PA[l * 3125 + (s * 25 + v) * 25 + u1] : 0.f;
            u4[h] = packbf(f0, f1);
        }
        *(uint4*)&PAfr[e * 4] = make_uint4(u4[0], u4[1], u4[2], u4[3]);
    }
    for (int i = tid; i < 768; i += 256)
        *(uint4*)&xtile[0][0][i * 8] = make_uint4(0, 0, 0, 0);
    if (tid < 128) bins[tid] = 0.f;

    bf16x8 Wf[3][5];
#pragma unroll
    for (int l = 0; l < 3; l++)
#pragma unroll
        for (int s = 0; s < 5; s++) {
            FRAG f;
            if (lg < 2)
                *(uint4*)f.u = *(const uint4*)(W2 + ((l * 5 + s) * 16 + lr) * 16 + lg * 8);
            else
                *(uint4*)f.u = make_uint4(0, 0, 0, 0);
            Wf[l][s] = f.v;
        }

    float a3[3], c3[3];
#pragma unroll
    for (int l = 0; l < 3; l++) { a3[l] = AC[l * 16 + lr]; c3[l] = AC[48 + l * 16 + lr]; }

    float cagg[4][4];
#pragma unroll
    for (int sI = 0; sI < 4; sI++)
#pragma unroll
        for (int r = 0; r < 4; r++) cagg[sI][r] = Cagg[sI * 16 + 4 * lg + r];

    f32x4 ss[4] = {}, qq[4] = {};
    const f32x4 zero = {};
    __syncthreads();   // PAfr + xtile zero-init visible to all waves

    const int wid = blockIdx.x * 4 + wave;
    for (int k = 0; k < 4; k++) {
        const int nt = wid * 4 + k;
#pragma unroll
        for (int it = 0; it < 3; it++) {
            int j = lane + it * 64;
            if (j < 150) {
                int l = j / 50, off = j - l * 50;
                *(uint4*)&xtile[wave][l][off * 8] =
                    *(const uint4*)(xdp + (size_t)l * XDP_ELEMS + (size_t)nt * 400 + off * 8);
            }
        }
        asm volatile("s_waitcnt lgkmcnt(0)" ::: "memory");
        __builtin_amdgcn_sched_barrier(0);

        f32x4 acc0[4] = {}, acc1[4] = {};
#pragma unroll
        for (int l = 0; l < 3; l++) {
            FRAG af;
#pragma unroll
            for (int h = 0; h < 4; h++) {
                int u0 = 8 * h + lg, u1 = 8 * h + 4 + lg;
                float x0 = bfu(xtile[wave][l][u0 * 16 + lr]);
                float x1 = bfu(xtile[wave][l][u1 * 16 + lr]);
                x0 = fmaxf(a3[l] * x0 + c3[l], 0.f);
                x1 = fmaxf(a3[l] * x1 + c3[l], 0.f);
                af.u[h] = packbf(x0, x1);
            }
            const bf16x8 A = af.v;

            f32x4 z0a, z0b;
#pragma unroll
            for (int s = 0; s < 5; s++) {
                FRAG bfA, bfB;
                *(uint4*)bfA.u = *(const uint4*)&PAfr[(((l * 5 + s) * 2 + 0) * 64 + lane) * 4];
                *(uint4*)bfB.u = *(const uint4*)&PAfr[(((l * 5 + s) * 2 + 1) * 64 + lane) * 4];
                f32x4 d0 = __builtin_amdgcn_mfma_f32_16x16x32_bf16(A, bfA.v, zero, 0, 0, 0);
                f32x4 d1 = __builtin_amdgcn_mfma_f32_16x16x32_bf16(A, bfB.v, zero, 0, 0, 0);
                bf16x8 b2a = reshapeM(d0, sA, sB);
                bf16x8 b2b = reshapeM(d1, sA, sB);
                f32x4 za = __builtin_amdgcn_mfma_f32_16x16x32_bf16(Wf[l][s], b2a, zero, 0, 0, 0);
                f32x4 zb = __builtin_amdgcn_mfma_f32_16x16x32_bf16(Wf[l][s], b2b, zero, 0, 0, 0);
                if (s == 0) { z0a = za; z0b = zb; }
                else {
                    acc0[s - 1] += za + z0a;
                    acc1[s - 1] += zb + z0b;
                }
            }
        }

        // bf16 acc write: [nt][v][64ch]; each (nt,v) row = 128B line.
        unsigned short* ab0 = accb + ((size_t)nt * 25 + lr) * 64;
        unsigned short* ab1 = accb + ((size_t)nt * 25 + 16 + lr) * 64;
#pragma unroll
        for (int sI = 0; sI < 4; sI++) {
            float v00 = acc0[sI][0] + cagg[sI][0];
            float v01 = acc0[sI][1] + cagg[sI][1];
            float v02 = acc0[sI][2] + cagg[sI][2];
            float v03 = acc0[sI][3] + cagg[sI][3];
            *(uint2*)(ab0 + sI * 16 + 4 * lg) =
                make_uint2(packbf(v00, v01), packbf(v02, v03));
            float v10 = acc1[sI][0] + cagg[sI][0];
            float v11 = acc1[sI][1] + cagg[sI][1];
            float v12 = acc1[sI][2] + cagg[sI][2];
            float v13 = acc1[sI][3] + cagg[sI][3];
            float u0 = (lr < 9) ? v10 : 0.f, u1 = (lr < 9) ? v11 : 0.f;
            float u2 = (lr < 9) ? v12 : 0.f, u3 = (lr < 9) ? v13 : 0.f;
            if (lr < 9)
                *(uint2*)(ab1 + sI * 16 + 4 * lg) =
                    make_uint2(packbf(v10, v11), packbf(v12, v13));
            ss[sI][0] += v00 + u0; qq[sI][0] += v00 * v00 + u0 * u0;
            ss[sI][1] += v01 + u1; qq[sI][1] += v01 * v01 + u1 * u1;
            ss[sI][2] += v02 + u2; qq[sI][2] += v02 * v02 + u2 * u2;
            ss[sI][3] += v03 + u3; qq[sI][3] += v03 * v03 + u3 * u3;
        }
    }

#pragma unroll
    for (int sI = 0; sI < 4; sI++)
#pragma unroll
        for (int r = 0; r < 4; r++) {
            float sv = ss[sI][r], qv = qq[sI][r];
            sv += __shfl_xor(sv, 1, 64); qv += __shfl_xor(qv, 1, 64);
            sv += __shfl_xor(sv, 2, 64); qv += __shfl_xor(qv, 2, 64);
            sv += __shfl_xor(sv, 4, 64); qv += __shfl_xor(qv, 4, 64);
            sv += __shfl_xor(sv, 8, 64); qv += __shfl_xor(qv, 8, 64);
            if (lr == 0) {
                atomicAdd(&bins[sI * 16 + 4 * lg + r], sv);
                atomicAdd(&bins[64 + sI * 16 + 4 * lg + r], qv);
            }
        }
    __syncthreads();
    if (tid < 128) atomicAdd(&stout[tid], bins[tid]);
}

// ---- K6: out = relu(bn(acc) + x), coalesced via LDS transpose (8 nt/block)
__global__ __launch_bounds__(256, 2) void k_final2(
    const unsigned short* __restrict__ accb, const float* __restrict__ x,
    const float* __restrict__ go, const float* __restrict__ bo,
    const float* __restrict__ stout, float* __restrict__ out)
{
    __shared__ float ao[64], co[64];
    __shared__ float tile[32][208];
    const int tid = threadIdx.x;
    if (tid < 64) {
        float m   = stout[tid] * (1.f / CNTF);
        float var = stout[64 + tid] * (1.f / CNTF) - m * m;
        float a   = go[tid] * rsqrtf(var + EPS);
        ao[tid] = a; co[tid] = bo[tid] - m * a;
    }

    const int nt0 = blockIdx.x * 8, n = nt0 >> 7, t0 = nt0 & 127;
    const int pp = tid / 25, v = tid - pp * 25;
    const unsigned short* arow = accb + ((size_t)(nt0 + pp) * 25 + v) * 64;

#pragma unroll
    for (int h = 0; h < 2; h++) {
        __syncthreads();   // ao/co ready (h=0) / prev-half tile reads done (h=1)
        if (tid < 200) {
#pragma unroll
            for (int j = 0; j < 4; j++) {
                uint4 w = *(const uint4*)(arow + h * 32 + j * 8);
                const int cb = h * 32 + j * 8;
                tile[j*8+0][tid] = ao[cb+0] * bfu(w.x & 0xffffu) + co[cb+0];
                tile[j*8+1][tid] = ao[cb+1] * bfu(w.x >> 16)     + co[cb+1];
                tile[j*8+2][tid] = ao[cb+2] * bfu(w.y & 0xffffu) + co[cb+2];
                tile[j*8+3][tid] = ao[cb+3] * bfu(w.y >> 16)     + co[cb+3];
                tile[j*8+4][tid] = ao[cb+4] * bfu(w.z & 0xffffu) + co[cb+4];
                tile[j*8+5][tid] = ao[cb+5] * bfu(w.z >> 16)     + co[cb+5];
                tile[j*8+6][tid] = ao[cb+6] * bfu(w.w & 0xffffu) + co[cb+6];
                tile[j*8+7][tid] = ao[cb+7] * bfu(w.w >> 16)     + co[cb+7];
            }
        }
        __syncthreads();
        for (int i = tid; i < 6400; i += 256) {
            int kk = i / 200, p = i - kk * 200;
            int adr = n * 204800 + (h * 32 + kk) * 3200 + t0 * 25 + p;
            out[adr] = fmaxf(tile[kk][p] + x[adr], 0.f);
        }
    }
}

extern "C" void kernel_launch(void* const* d_in, const int* in_sizes, int n_in,
                              void* d_out, int out_size, void* d_ws, size_t ws_size,
                              hipStream_t stream)
{
    const float* x     = (const float*)d_in[0];
    const float* PA    = (const float*)d_in[1];
    const float* Wd    = (const float*)d_in[2];
    const float* gd    = (const float*)d_in[4];
    const float* betad = (const float*)d_in[5];
    const float* Wsub  = (const float*)d_in[6];
    const float* gsub  = (const float*)d_in[8];
    const float* betas = (const float*)d_in[9];
    const float* gout  = (const float*)d_in[10];
    const float* betao = (const float*)d_in[11];
    float* out = (float*)d_out;

    unsigned short* xdp  = (unsigned short*)d_ws;            // 39.3 MB
    unsigned short* accb = xdp + (size_t)3 * XDP_ELEMS;      // 52.4 MB bf16
    float* st    = (float*)(accb + (size_t)ACC_ELEMS);
    float* AC    = st + 96;
    float* stq   = AC + 96;       // [3][160]
    float* stout = stq + 480;     // [128]
    float* Wtg   = stout + 128;   // [64][48]
    float* Cagg  = Wtg + 3072;    // [64]
    unsigned short* W2 = (unsigned short*)(Cagg + 64);  // [3][80][16] bf16

    hipMemsetAsync(st, 0, (96 + 96 + 480 + 128) * sizeof(float), stream);

    k_prep   <<<1,   256, 0, stream>>>(Wd, Wtg);
    k_down3  <<<800, 256, 0, stream>>>(x, Wtg, xdp, st);
    k_findown<<<1,    64, 0, stream>>>(st, gd, betad, AC);

    for (int l = 0; l < 3; l++)
        k_zstats<<<1024, 256, 0, stream>>>(xdp + (size_t)l * XDP_ELEMS, PA + l * 3125,
                                           Wsub + l * 1280, AC + l * 16, AC + 48 + l * 16,
                                           stq + l * 160);
    k_finsub  <<<1,    256, 0, stream>>>(stq, Wsub, gsub, betas, W2, Cagg);
    k_out_mfma<<<1024, 256, 0, stream>>>(xdp, PA, W2, Cagg, AC, stout, accb);
    k_final2  <<<2048, 256, 0, stream>>>(accb, x, gout, betao, stout, out);
}

// Round 14
// 415.644 us; speedup vs baseline: 1.1610x; 1.1238x over previous
//
#include <hip/hip_runtime.h>

#define EPS  1e-5f
#define CNTF 409600.0f            // N*T*V
#define XDP_ELEMS 6553600         // per layer: 16384 nt * 400, layout [nt][u][16o]
#define ACC_ELEMS 26214400        // 16384 nt * 25 v * 64 ch (bf16)

typedef short bf16x8 __attribute__((ext_vector_type(8)));
typedef float f32x4  __attribute__((ext_vector_type(4)));

union FRAG { unsigned int u[4]; bf16x8 v; };

__device__ __forceinline__ float wave_sum(float v) {
#pragma unroll
    for (int off = 32; off > 0; off >>= 1)
        v += __shfl_down(v, off, 64);
    return v;
}

__device__ __forceinline__ float bfu(unsigned int u16) {
    union { unsigned int i; float f; } x;
    x.i = u16 << 16;
    return x.f;
}
__device__ __forceinline__ unsigned int f2bf(float f) {
    union { float f; unsigned int i; } u; u.f = f;
    unsigned int r = u.i + 0x7fff + ((u.i >> 16) & 1);
    return r >> 16;
}
__device__ __forceinline__ unsigned int packbf(float a, float b) {
    return f2bf(a) | (f2bf(b) << 16);
}

// Pack MFMA1's D-register directly as the second MFMA's B operand.
// Bijection for GEMM2: k-slot (lg, elem r<4) <-> c = 4*lg + r; elems 4..7 pad(0).
__device__ __forceinline__ bf16x8 packD(const f32x4 d) {
    FRAG f;
    f.u[0] = packbf(d[0], d[1]);
    f.u[1] = packbf(d[2], d[3]);
    f.u[2] = 0u;
    f.u[3] = 0u;
    return f.v;
}

// ---- K0: transpose W_down into [c][48] so k_down3 can scalar-load it
__global__ __launch_bounds__(256) void k_prep(const float* __restrict__ Wd,
                                              float* __restrict__ Wtg)
{
    for (int j = threadIdx.x; j < 3072; j += 256) {
        int c = j / 48, k = j - c * 48;
        int l = k / 16, o = k - l * 16;
        Wtg[j] = Wd[l * 1024 + o * 64 + c];
    }
}

// ---- K1: conv_down all 3 layers (bias cancels in BN), bf16 xd + stats.
__global__ __launch_bounds__(256) void k_down3(
    const float* __restrict__ x, const float* __restrict__ Wtg,
    unsigned short* __restrict__ xdp, float* __restrict__ st /*96*/)
{
    __shared__ float bins[96];
    const int tid = threadIdx.x;
    if (tid < 96) bins[tid] = 0.f;
    __syncthreads();

    const int base = (blockIdx.x * 256 + tid) * 2;
    const int n = base / 3200, pb = base - n * 3200;
    const float* xb = x + n * 204800 + pb;

    float acc0[48], acc1[48];
#pragma unroll
    for (int k = 0; k < 48; k++) { acc0[k] = 0.f; acc1[k] = 0.f; }

    for (int c = 0; c < 64; c++) {
        float2 xv = *(const float2*)&xb[c * 3200];
        const float4* wr = (const float4*)(Wtg + c * 48);   // uniform -> s_load
#pragma unroll
        for (int q = 0; q < 12; q++) {
            float4 w = wr[q];
            acc0[4*q+0] += w.x * xv.x;  acc1[4*q+0] += w.x * xv.y;
            acc0[4*q+1] += w.y * xv.x;  acc1[4*q+1] += w.y * xv.y;
            acc0[4*q+2] += w.z * xv.x;  acc1[4*q+2] += w.z * xv.y;
            acc0[4*q+3] += w.w * xv.x;  acc1[4*q+3] += w.w * xv.y;
        }
    }
#pragma unroll
    for (int l = 0; l < 3; l++) {
        unsigned int pk0[8], pk1[8];
#pragma unroll
        for (int h = 0; h < 8; h++) {
            pk0[h] = packbf(acc0[l*16 + 2*h], acc0[l*16 + 2*h + 1]);
            pk1[h] = packbf(acc1[l*16 + 2*h], acc1[l*16 + 2*h + 1]);
        }
        uint4* dst = (uint4*)(xdp + (size_t)l * XDP_ELEMS + (size_t)base * 16);
        dst[0] = make_uint4(pk0[0], pk0[1], pk0[2], pk0[3]);
        dst[1] = make_uint4(pk0[4], pk0[5], pk0[6], pk0[7]);
        dst[2] = make_uint4(pk1[0], pk1[1], pk1[2], pk1[3]);
        dst[3] = make_uint4(pk1[4], pk1[5], pk1[6], pk1[7]);
    }

    const int lane = tid & 63;
#pragma unroll
    for (int k = 0; k < 48; k++) {
        float sv = wave_sum(acc0[k] + acc1[k]);
        float qv = wave_sum(acc0[k] * acc0[k] + acc1[k] * acc1[k]);
        if (lane == 0) { atomicAdd(&bins[k], sv); atomicAdd(&bins[48 + k], qv); }
    }
    __syncthreads();
    if (tid < 96) atomicAdd(&st[tid], bins[tid]);
}

// ---- K2: finalize down affines
__global__ __launch_bounds__(64) void k_findown(
    const float* __restrict__ st, const float* __restrict__ gd,
    const float* __restrict__ betad, float* __restrict__ AC)
{
    int t = threadIdx.x;
    if (t < 48) {
        float m   = st[t] * (1.f / CNTF);
        float var = st[48 + t] * (1.f / CNTF) - m * m;
        float a   = gd[t] * rsqrtf(var + EPS);
        AC[t]      = a;
        AC[48 + t] = betad[t] - a * m;
    }
}

// ---- K3: per-layer z stats via MFMA. GEMM2 consumes packed D directly
// (matching bijection) -> no cross-lane reshape at all.
__global__ __launch_bounds__(256, 1) void k_zstats(
    const unsigned short* __restrict__ xd,   // [nt][u<25][16c] bf16
    const float* __restrict__ PAl,           // [5][25][25]
    const float* __restrict__ Wsl,           // [80][16]
    const float* __restrict__ Al, const float* __restrict__ Cl,
    float* __restrict__ stql)                // [160]
{
    __shared__ unsigned short xtile[4][512];
    __shared__ float bins[160];

    const int tid  = threadIdx.x;
    const int wave = tid >> 6, lane = tid & 63;
    const int lr = lane & 15, lg = lane >> 4;

    *(uint4*)&xtile[tid >> 6][(tid & 63) * 8] = make_uint4(0, 0, 0, 0);
    for (int i = tid; i < 160; i += 256) bins[i] = 0.f;
    __syncthreads();

    bf16x8 Bfrag[5][2];
#pragma unroll
    for (int s = 0; s < 5; s++)
#pragma unroll
        for (int t = 0; t < 2; t++) {
            FRAG f;
            const int v = t * 16 + lr;
#pragma unroll
            for (int h = 0; h < 4; h++) {
                int u0 = 8 * h + lg, u1 = 8 * h + 4 + lg;
                float f0 = (v < 25 && u0 < 25) ? PAl[(s * 25 + v) * 25 + u0] : 0.f;
                float f1 = (v < 25 && u1 < 25) ? PAl[(s * 25 + v) * 25 + u1] : 0.f;
                f.u[h] = packbf(f0, f1);
            }
            Bfrag[s][t] = f.v;
        }

    // GEMM2 A-operand (W): elem r<4 = W[o=lr][c=4*lg+r], elems 4..7 = 0
    bf16x8 Wfrag[5];
#pragma unroll
    for (int s = 0; s < 5; s++) {
        FRAG f;
        const float* wr = Wsl + (s * 16 + lr) * 16 + 4 * lg;
        f.u[0] = packbf(wr[0], wr[1]);
        f.u[1] = packbf(wr[2], wr[3]);
        f.u[2] = 0u; f.u[3] = 0u;
        Wfrag[s] = f.v;
    }

    const float a_c = Al[lr], c_c = Cl[lr];

    f32x4 sacc[5] = {};
    f32x4 qacc[5] = {};
    const f32x4 zero = {};

    const int wid = blockIdx.x * 4 + wave;
    for (int k = 0; k < 4; k++) {
        const int nt = wid * 4 + k;
        if (lane < 50)
            *(uint4*)&xtile[wave][lane * 8] =
                *(const uint4*)(xd + (size_t)nt * 400 + lane * 8);
        asm volatile("s_waitcnt lgkmcnt(0)" ::: "memory");
        __builtin_amdgcn_sched_barrier(0);

        FRAG af;
#pragma unroll
        for (int h = 0; h < 4; h++) {
            int u0 = 8 * h + lg, u1 = 8 * h + 4 + lg;
            float x0 = bfu(xtile[wave][u0 * 16 + lr]);
            float x1 = bfu(xtile[wave][u1 * 16 + lr]);
            x0 = fmaxf(a_c * x0 + c_c, 0.f);
            x1 = fmaxf(a_c * x1 + c_c, 0.f);
            af.u[h] = packbf(x0, x1);
        }
        const bf16x8 A = af.v;

#pragma unroll
        for (int s = 0; s < 5; s++) {
            f32x4 d0 = __builtin_amdgcn_mfma_f32_16x16x32_bf16(A, Bfrag[s][0], zero, 0, 0, 0);
            f32x4 d1 = __builtin_amdgcn_mfma_f32_16x16x32_bf16(A, Bfrag[s][1], zero, 0, 0, 0);
            f32x4 z0 = __builtin_amdgcn_mfma_f32_16x16x32_bf16(Wfrag[s], packD(d0), zero, 0, 0, 0);
            f32x4 z1 = __builtin_amdgcn_mfma_f32_16x16x32_bf16(Wfrag[s], packD(d1), zero, 0, 0, 0);
            sacc[s] += z0; qacc[s] += z0 * z0;
            if (lr < 9) { sacc[s] += z1; qacc[s] += z1 * z1; }
        }
    }

#pragma unroll
    for (int s = 0; s < 5; s++)
#pragma unroll
        for (int r = 0; r < 4; r++) {
            float sv = sacc[s][r], qv = qacc[s][r];
            sv += __shfl_xor(sv, 1, 64); qv += __shfl_xor(qv, 1, 64);
            sv += __shfl_xor(sv, 2, 64); qv += __shfl_xor(qv, 2, 64);
            sv += __shfl_xor(sv, 4, 64); qv += __shfl_xor(qv, 4, 64);
            sv += __shfl_xor(sv, 8, 64); qv += __shfl_xor(qv, 8, 64);
            if (lr == 0) {
                atomicAdd(&bins[s * 16 + 4 * lg + r], sv);
                atomicAdd(&bins[80 + s * 16 + 4 * lg + r], qv);
            }
        }
    __syncthreads();
    for (int i = tid; i < 160; i += 256) atomicAdd(&stql[i], bins[i]);
}

// ---- K4: fold sub-BN affine into W (W2 = A*W, bf16) and constants into Cagg[64]
__global__ __launch_bounds__(256) void k_finsub(
    const float* __restrict__ stq,    // [3][160]
    const float* __restrict__ Wsub,   // [3][80][16]
    const float* __restrict__ gs, const float* __restrict__ betas,
    unsigned short* __restrict__ W2,  // [3][80][16] bf16 (A-scaled)
    float* __restrict__ Cagg)         // [64]
{
    __shared__ float As[240], Cs[240];
    const int tid = threadIdx.x;
    if (tid < 240) {
        int l = tid / 80, ch = tid - l * 80;
        float m   = stq[l * 160 + ch] * (1.f / CNTF);
        float var = stq[l * 160 + 80 + ch] * (1.f / CNTF) - m * m;
        float a   = gs[l * 80 + ch] * rsqrtf(var + EPS);
        As[tid] = a;
        Cs[tid] = betas[l * 80 + ch] - a * m;
    }
    __syncthreads();
    for (int i = tid; i < 3840; i += 256) {
        int l = i / 1280, r = i - l * 1280, ch = r / 16;
        W2[i] = (unsigned short)f2bf(As[l * 80 + ch] * Wsub[i]);
    }
    if (tid < 64) {
        int sIdx = tid >> 4, o = tid & 15;
        float c = 0.f;
        for (int l = 0; l < 3; l++)
            c += Cs[l * 80 + (sIdx + 1) * 16 + o] + Cs[l * 80 + o];
        Cagg[tid] = c;
    }
}

// ---- K5: fused 3-layer output via MFMA -> bf16 acc [nt][v][64] + final-BN stats.
__global__ __launch_bounds__(256, 1) void k_out_mfma(
    const unsigned short* __restrict__ xdp,  // [3][nt][u<25][16c]
    const float* __restrict__ PA,            // [3][5][25][25]
    const unsigned short* __restrict__ W2,   // [3][80][16] bf16
    const float* __restrict__ Cagg,          // [64]
    const float* __restrict__ AC,            // [96] down affines
    float* __restrict__ stout,               // [128]
    unsigned short* __restrict__ accb)       // [nt][25][64] bf16
{
    __shared__ unsigned int PAfr[30 * 64 * 4];     // 30 frags x 64 lanes x uint4
    __shared__ unsigned short xtile[4][3][512];
    __shared__ float bins[128];

    const int tid  = threadIdx.x;
    const int wave = tid >> 6, lane = tid & 63;
    const int lr = lane & 15, lg = lane >> 4;

    for (int e = tid; e < 1920; e += 256) {
        int frag = e >> 6, ln = e & 63;
        int l = frag / 10, rem = frag - l * 10;
        int s = rem >> 1, t = rem & 1;
        int elr = ln & 15, elg = ln >> 4;
        int v = t * 16 + elr;
        unsigned int u4[4];
#pragma unroll
        for (int h = 0; h < 4; h++) {
            int u0 = 8 * h + elg, u1 = 8 * h + 4 + elg;
            float f0 = (v < 25 && u0 < 25) ? PA[l * 3125 + (s * 25 + v) * 25 + u0] : 0.f;
            float f1 = (v < 25 && u1 < 25) ? PA[l * 3125 + (s * 25 + v) * 25 + u1] : 0.f;
            u4[h] = packbf(f0, f1);
        }
        *(uint4*)&PAfr[e * 4] = make_uint4(u4[0], u4[1], u4[2], u4[3]);
    }
    for (int i = tid; i < 768; i += 256)
        *(uint4*)&xtile[0][0][i * 8] = make_uint4(0, 0, 0, 0);
    if (tid < 128) bins[tid] = 0.f;

    // GEMM2 A-operand (pre-scaled W): elem r<4 = W2[o=lr][4*lg+r], rest 0
    bf16x8 Wf[3][5];
#pragma unroll
    for (int l = 0; l < 3; l++)
#pragma unroll
        for (int s = 0; s < 5; s++) {
            FRAG f;
            const uint2 w = *(const uint2*)(W2 + ((l * 5 + s) * 16 + lr) * 16 + 4 * lg);
            f.u[0] = w.x; f.u[1] = w.y; f.u[2] = 0u; f.u[3] = 0u;
            Wf[l][s] = f.v;
        }

    float a3[3], c3[3];
#pragma unroll
    for (int l = 0; l < 3; l++) { a3[l] = AC[l * 16 + lr]; c3[l] = AC[48 + l * 16 + lr]; }

    float cagg[4][4];
#pragma unroll
    for (int sI = 0; sI < 4; sI++)
#pragma unroll
        for (int r = 0; r < 4; r++) cagg[sI][r] = Cagg[sI * 16 + 4 * lg + r];

    f32x4 ss[4] = {}, qq[4] = {};
    const f32x4 zero = {};
    __syncthreads();   // PAfr + xtile zero-init visible to all waves

    const int wid = blockIdx.x * 4 + wave;
    for (int k = 0; k < 4; k++) {
        const int nt = wid * 4 + k;
#pragma unroll
        for (int it = 0; it < 3; it++) {
            int j = lane + it * 64;
            if (j < 150) {
                int l = j / 50, off = j - l * 50;
                *(uint4*)&xtile[wave][l][off * 8] =
                    *(const uint4*)(xdp + (size_t)l * XDP_ELEMS + (size_t)nt * 400 + off * 8);
            }
        }
        asm volatile("s_waitcnt lgkmcnt(0)" ::: "memory");
        __builtin_amdgcn_sched_barrier(0);

        f32x4 acc0[4] = {}, acc1[4] = {};
#pragma unroll
        for (int l = 0; l < 3; l++) {
            FRAG af;
#pragma unroll
            for (int h = 0; h < 4; h++) {
                int u0 = 8 * h + lg, u1 = 8 * h + 4 + lg;
                float x0 = bfu(xtile[wave][l][u0 * 16 + lr]);
                float x1 = bfu(xtile[wave][l][u1 * 16 + lr]);
                x0 = fmaxf(a3[l] * x0 + c3[l], 0.f);
                x1 = fmaxf(a3[l] * x1 + c3[l], 0.f);
                af.u[h] = packbf(x0, x1);
            }
            const bf16x8 A = af.v;

            f32x4 z0a, z0b;
#pragma unroll
            for (int s = 0; s < 5; s++) {
                FRAG bfA, bfB;
                *(uint4*)bfA.u = *(const uint4*)&PAfr[(((l * 5 + s) * 2 + 0) * 64 + lane) * 4];
                *(uint4*)bfB.u = *(const uint4*)&PAfr[(((l * 5 + s) * 2 + 1) * 64 + lane) * 4];
                f32x4 d0 = __builtin_amdgcn_mfma_f32_16x16x32_bf16(A, bfA.v, zero, 0, 0, 0);
                f32x4 d1 = __builtin_amdgcn_mfma_f32_16x16x32_bf16(A, bfB.v, zero, 0, 0, 0);
                f32x4 za = __builtin_amdgcn_mfma_f32_16x16x32_bf16(Wf[l][s], packD(d0), zero, 0, 0, 0);
                f32x4 zb = __builtin_amdgcn_mfma_f32_16x16x32_bf16(Wf[l][s], packD(d1), zero, 0, 0, 0);
                if (s == 0) { z0a = za; z0b = zb; }
                else {
                    acc0[s - 1] += za + z0a;
                    acc1[s - 1] += zb + z0b;
                }
            }
        }

        // bf16 acc write: [nt][v][64ch]; each (nt,v) row = 128B line.
        unsigned short* ab0 = accb + ((size_t)nt * 25 + lr) * 64;
        unsigned short* ab1 = accb + ((size_t)nt * 25 + 16 + lr) * 64;
#pragma unroll
        for (int sI = 0; sI < 4; sI++) {
            float v00 = acc0[sI][0] + cagg[sI][0];
            float v01 = acc0[sI][1] + cagg[sI][1];
            float v02 = acc0[sI][2] + cagg[sI][2];
            float v03 = acc0[sI][3] + cagg[sI][3];
            *(uint2*)(ab0 + sI * 16 + 4 * lg) =
                make_uint2(packbf(v00, v01), packbf(v02, v03));
            float v10 = acc1[sI][0] + cagg[sI][0];
            float v11 = acc1[sI][1] + cagg[sI][1];
            float v12 = acc1[sI][2] + cagg[sI][2];
            float v13 = acc1[sI][3] + cagg[sI][3];
            float u0 = (lr < 9) ? v10 : 0.f, u1 = (lr < 9) ? v11 : 0.f;
            float u2 = (lr < 9) ? v12 : 0.f, u3 = (lr < 9) ? v13 : 0.f;
            if (lr < 9)
                *(uint2*)(ab1 + sI * 16 + 4 * lg) =
                    make_uint2(packbf(v10, v11), packbf(v12, v13));
            ss[sI][0] += v00 + u0; qq[sI][0] += v00 * v00 + u0 * u0;
            ss[sI][1] += v01 + u1; qq[sI][1] += v01 * v01 + u1 * u1;
            ss[sI][2] += v02 + u2; qq[sI][2] += v02 * v02 + u2 * u2;
            ss[sI][3] += v03 + u3; qq[sI][3] += v03 * v03 + u3 * u3;
        }
    }

#pragma unroll
    for (int sI = 0; sI < 4; sI++)
#pragma unroll
        for (int r = 0; r < 4; r++) {
            float sv = ss[sI][r], qv = qq[sI][r];
            sv += __shfl_xor(sv, 1, 64); qv += __shfl_xor(qv, 1, 64);
            sv += __shfl_xor(sv, 2, 64); qv += __shfl_xor(qv, 2, 64);
            sv += __shfl_xor(sv, 4, 64); qv += __shfl_xor(qv, 4, 64);
            sv += __shfl_xor(sv, 8, 64); qv += __shfl_xor(qv, 8, 64);
            if (lr == 0) {
                atomicAdd(&bins[sI * 16 + 4 * lg + r], sv);
                atomicAdd(&bins[64 + sI * 16 + 4 * lg + r], qv);
            }
        }
    __syncthreads();
    if (tid < 128) atomicAdd(&stout[tid], bins[tid]);
}

// ---- K6: out = relu(bn(acc) + x), coalesced via LDS transpose (8 nt/block)
__global__ __launch_bounds__(256, 2) void k_final2(
    const unsigned short* __restrict__ accb, const float* __restrict__ x,
    const float* __restrict__ go, const float* __restrict__ bo,
    const float* __restrict__ stout, float* __restrict__ out)
{
    __shared__ float ao[64], co[64];
    __shared__ float tile[32][208];
    const int tid = threadIdx.x;
    if (tid < 64) {
        float m   = stout[tid] * (1.f / CNTF);
        float var = stout[64 + tid] * (1.f / CNTF) - m * m;
        float a   = go[tid] * rsqrtf(var + EPS);
        ao[tid] = a; co[tid] = bo[tid] - m * a;
    }

    const int nt0 = blockIdx.x * 8, n = nt0 >> 7, t0 = nt0 & 127;
    const int pp = tid / 25, v = tid - pp * 25;
    const unsigned short* arow = accb + ((size_t)(nt0 + pp) * 25 + v) * 64;

#pragma unroll
    for (int h = 0; h < 2; h++) {
        __syncthreads();   // ao/co ready (h=0) / prev-half tile reads done (h=1)
        if (tid < 200) {
#pragma unroll
            for (int j = 0; j < 4; j++) {
                uint4 w = *(const uint4*)(arow + h * 32 + j * 8);
                const int cb = h * 32 + j * 8;
                tile[j*8+0][tid] = ao[cb+0] * bfu(w.x & 0xffffu) + co[cb+0];
                tile[j*8+1][tid] = ao[cb+1] * bfu(w.x >> 16)     + co[cb+1];
                tile[j*8+2][tid] = ao[cb+2] * bfu(w.y & 0xffffu) + co[cb+2];
                tile[j*8+3][tid] = ao[cb+3] * bfu(w.y >> 16)     + co[cb+3];
                tile[j*8+4][tid] = ao[cb+4] * bfu(w.z & 0xffffu) + co[cb+4];
                tile[j*8+5][tid] = ao[cb+5] * bfu(w.z >> 16)     + co[cb+5];
                tile[j*8+6][tid] = ao[cb+6] * bfu(w.w & 0xffffu) + co[cb+6];
                tile[j*8+7][tid] = ao[cb+7] * bfu(w.w >> 16)     + co[cb+7];
            }
        }
        __syncthreads();
        for (int i = tid; i < 6400; i += 256) {
            int kk = i / 200, p = i - kk * 200;
            int adr = n * 204800 + (h * 32 + kk) * 3200 + t0 * 25 + p;
            out[adr] = fmaxf(tile[kk][p] + x[adr], 0.f);
        }
    }
}

extern "C" void kernel_launch(void* const* d_in, const int* in_sizes, int n_in,
                              void* d_out, int out_size, void* d_ws, size_t ws_size,
                              hipStream_t stream)
{
    const float* x     = (const float*)d_in[0];
    const float* PA    = (const float*)d_in[1];
    const float* Wd    = (const float*)d_in[2];
    const float* gd    = (const float*)d_in[4];
    const float* betad = (const float*)d_in[5];
    const float* Wsub  = (const float*)d_in[6];
    const float* gsub  = (const float*)d_in[8];
    const float* betas = (const float*)d_in[9];
    const float* gout  = (const float*)d_in[10];
    const float* betao = (const float*)d_in[11];
    float* out = (float*)d_out;

    unsigned short* xdp  = (unsigned short*)d_ws;            // 39.3 MB
    unsigned short* accb = xdp + (size_t)3 * XDP_ELEMS;      // 52.4 MB bf16
    float* st    = (float*)(accb + (size_t)ACC_ELEMS);
    float* AC    = st + 96;
    float* stq   = AC + 96;       // [3][160]
    float* stout = stq + 480;     // [128]
    float* Wtg   = stout + 128;   // [64][48]
    float* Cagg  = Wtg + 3072;    // [64]
    unsigned short* W2 = (unsigned short*)(Cagg + 64);  // [3][80][16] bf16

    hipMemsetAsync(st, 0, (96 + 96 + 480 + 128) * sizeof(float), stream);

    k_prep   <<<1,   256, 0, stream>>>(Wd, Wtg);
    k_down3  <<<800, 256, 0, stream>>>(x, Wtg, xdp, st);
    k_findown<<<1,    64, 0, stream>>>(st, gd, betad, AC);

    for (int l = 0; l < 3; l++)
        k_zstats<<<1024, 256, 0, stream>>>(xdp + (size_t)l * XDP_ELEMS, PA + l * 3125,
                                           Wsub + l * 1280, AC + l * 16, AC + 48 + l * 16,
                                           stq + l * 160);
    k_finsub  <<<1,    256, 0, stream>>>(stq, Wsub, gsub, betas, W2, Cagg);
    k_out_mfma<<<1024, 256, 0, stream>>>(xdp, PA, W2, Cagg, AC, stout, accb);
    k_final2  <<<2048, 256, 0, stream>>>(accb, x, gout, betao, stout, out);
}

// Round 15
// 383.802 us; speedup vs baseline: 1.2573x; 1.0830x over previous
//
#include <hip/hip_runtime.h>

#define EPS  1e-5f
#define CNTF 409600.0f            // N*T*V
#define XDP_ELEMS 6553600         // per layer: 16384 nt * 400, layout [nt][u][16o]
#define ACC_ELEMS 26214400        // 16384 nt * 25 v * 64 ch (bf16)

typedef short bf16x8 __attribute__((ext_vector_type(8)));
typedef float f32x4  __attribute__((ext_vector_type(4)));

union FRAG { unsigned int u[4]; bf16x8 v; };

__device__ __forceinline__ float wave_sum(float v) {
#pragma unroll
    for (int off = 32; off > 0; off >>= 1)
        v += __shfl_down(v, off, 64);
    return v;
}

__device__ __forceinline__ float bfu(unsigned int u16) {
    union { unsigned int i; float f; } x;
    x.i = u16 << 16;
    return x.f;
}
__device__ __forceinline__ unsigned int f2bf(float f) {
    union { float f; unsigned int i; } u; u.f = f;
    unsigned int r = u.i + 0x7fff + ((u.i >> 16) & 1);
    return r >> 16;
}
__device__ __forceinline__ unsigned int packbf(float a, float b) {
    return f2bf(a) | (f2bf(b) << 16);
}

// Pack MFMA1's D-register directly as the second MFMA's B operand.
// Bijection for GEMM2: k-slot (lg, elem r<4) <-> c = 4*lg + r; elems 4..7 pad(0).
__device__ __forceinline__ bf16x8 packD(const f32x4 d) {
    FRAG f;
    f.u[0] = packbf(d[0], d[1]);
    f.u[1] = packbf(d[2], d[3]);
    f.u[2] = 0u;
    f.u[3] = 0u;
    return f.v;
}

// ---- K0: transpose W_down into [c][48] so k_down3 can scalar-load it
__global__ __launch_bounds__(256) void k_prep(const float* __restrict__ Wd,
                                              float* __restrict__ Wtg)
{
    for (int j = threadIdx.x; j < 3072; j += 256) {
        int c = j / 48, k = j - c * 48;
        int l = k / 16, o = k - l * 16;
        Wtg[j] = Wd[l * 1024 + o * 64 + c];
    }
}

// ---- K1: conv_down all 3 layers (bias cancels in BN), bf16 xd + stats.
__global__ __launch_bounds__(256) void k_down3(
    const float* __restrict__ x, const float* __restrict__ Wtg,
    unsigned short* __restrict__ xdp, float* __restrict__ st /*96*/)
{
    __shared__ float bins[96];
    const int tid = threadIdx.x;
    if (tid < 96) bins[tid] = 0.f;
    __syncthreads();

    const int base = (blockIdx.x * 256 + tid) * 2;
    const int n = base / 3200, pb = base - n * 3200;
    const float* xb = x + n * 204800 + pb;

    float acc0[48], acc1[48];
#pragma unroll
    for (int k = 0; k < 48; k++) { acc0[k] = 0.f; acc1[k] = 0.f; }

    for (int c = 0; c < 64; c++) {
        float2 xv = *(const float2*)&xb[c * 3200];
        const float4* wr = (const float4*)(Wtg + c * 48);   // uniform -> s_load
#pragma unroll
        for (int q = 0; q < 12; q++) {
            float4 w = wr[q];
            acc0[4*q+0] += w.x * xv.x;  acc1[4*q+0] += w.x * xv.y;
            acc0[4*q+1] += w.y * xv.x;  acc1[4*q+1] += w.y * xv.y;
            acc0[4*q+2] += w.z * xv.x;  acc1[4*q+2] += w.z * xv.y;
            acc0[4*q+3] += w.w * xv.x;  acc1[4*q+3] += w.w * xv.y;
        }
    }
#pragma unroll
    for (int l = 0; l < 3; l++) {
        unsigned int pk0[8], pk1[8];
#pragma unroll
        for (int h = 0; h < 8; h++) {
            pk0[h] = packbf(acc0[l*16 + 2*h], acc0[l*16 + 2*h + 1]);
            pk1[h] = packbf(acc1[l*16 + 2*h], acc1[l*16 + 2*h + 1]);
        }
        uint4* dst = (uint4*)(xdp + (size_t)l * XDP_ELEMS + (size_t)base * 16);
        dst[0] = make_uint4(pk0[0], pk0[1], pk0[2], pk0[3]);
        dst[1] = make_uint4(pk0[4], pk0[5], pk0[6], pk0[7]);
        dst[2] = make_uint4(pk1[0], pk1[1], pk1[2], pk1[3]);
        dst[3] = make_uint4(pk1[4], pk1[5], pk1[6], pk1[7]);
    }

    const int lane = tid & 63;
#pragma unroll
    for (int k = 0; k < 48; k++) {
        float sv = wave_sum(acc0[k] + acc1[k]);
        float qv = wave_sum(acc0[k] * acc0[k] + acc1[k] * acc1[k]);
        if (lane == 0) { atomicAdd(&bins[k], sv); atomicAdd(&bins[48 + k], qv); }
    }
    __syncthreads();
    if (tid < 96) atomicAdd(&st[tid], bins[tid]);
}

// ---- K2: finalize down affines
__global__ __launch_bounds__(64) void k_findown(
    const float* __restrict__ st, const float* __restrict__ gd,
    const float* __restrict__ betad, float* __restrict__ AC)
{
    int t = threadIdx.x;
    if (t < 48) {
        float m   = st[t] * (1.f / CNTF);
        float var = st[48 + t] * (1.f / CNTF) - m * m;
        float a   = gd[t] * rsqrtf(var + EPS);
        AC[t]      = a;
        AC[48 + t] = betad[t] - a * m;
    }
}

// ---- K3: ALL-layer z stats via MFMA (fused; layer = blockIdx>>10).
// Register prefetch (T14): ds_write staged regs, issue next-nt loads, then
// lgkmcnt(0) waits only the LDS write - HBM latency hides under compute.
__global__ __launch_bounds__(256, 1) void k_zstats3(
    const unsigned short* __restrict__ xdp,  // [3][nt][u<25][16c] bf16
    const float* __restrict__ PA,            // [3][5][25][25]
    const float* __restrict__ Wsub,          // [3][80][16]
    const float* __restrict__ AC,            // [96]
    float* __restrict__ stq)                 // [3][160]
{
    __shared__ unsigned short xtile[4][512];
    __shared__ float bins[160];

    const int l   = blockIdx.x >> 10;
    const int blk = blockIdx.x & 1023;
    const unsigned short* xd = xdp + (size_t)l * XDP_ELEMS;
    const float* PAl = PA + l * 3125;
    const float* Wsl = Wsub + l * 1280;

    const int tid  = threadIdx.x;
    const int wave = tid >> 6, lane = tid & 63;
    const int lr = lane & 15, lg = lane >> 4;

    *(uint4*)&xtile[tid >> 6][(tid & 63) * 8] = make_uint4(0, 0, 0, 0);
    for (int i = tid; i < 160; i += 256) bins[i] = 0.f;
    __syncthreads();

    bf16x8 Bfrag[5][2];
#pragma unroll
    for (int s = 0; s < 5; s++)
#pragma unroll
        for (int t = 0; t < 2; t++) {
            FRAG f;
            const int v = t * 16 + lr;
#pragma unroll
            for (int h = 0; h < 4; h++) {
                int u0 = 8 * h + lg, u1 = 8 * h + 4 + lg;
                float f0 = (v < 25 && u0 < 25) ? PAl[(s * 25 + v) * 25 + u0] : 0.f;
                float f1 = (v < 25 && u1 < 25) ? PAl[(s * 25 + v) * 25 + u1] : 0.f;
                f.u[h] = packbf(f0, f1);
            }
            Bfrag[s][t] = f.v;
        }

    // GEMM2 A-operand (W): elem r<4 = W[o=lr][c=4*lg+r], elems 4..7 = 0
    bf16x8 Wfrag[5];
#pragma unroll
    for (int s = 0; s < 5; s++) {
        FRAG f;
        const float* wr = Wsl + (s * 16 + lr) * 16 + 4 * lg;
        f.u[0] = packbf(wr[0], wr[1]);
        f.u[1] = packbf(wr[2], wr[3]);
        f.u[2] = 0u; f.u[3] = 0u;
        Wfrag[s] = f.v;
    }

    const float a_c = AC[l * 16 + lr], c_c = AC[48 + l * 16 + lr];

    f32x4 sacc[5] = {};
    f32x4 qacc[5] = {};
    const f32x4 zero = {};

    const int wid = blk * 4 + wave;
    const unsigned short* sbase = xd + lane * 8;   // + nt*400
    unsigned short* dstp = &xtile[wave][lane * 8];
    uint4 pre = make_uint4(0, 0, 0, 0);
    if (lane < 50) pre = *(const uint4*)(sbase + (size_t)(wid * 4) * 400);

    for (int k = 0; k < 4; k++) {
        if (lane < 50) *(uint4*)dstp = pre;
        if (k < 3 && lane < 50)
            pre = *(const uint4*)(sbase + (size_t)(wid * 4 + k + 1) * 400);
        asm volatile("s_waitcnt lgkmcnt(0)" ::: "memory");
        __builtin_amdgcn_sched_barrier(0);

        FRAG af;
#pragma unroll
        for (int h = 0; h < 4; h++) {
            int u0 = 8 * h + lg, u1 = 8 * h + 4 + lg;
            float x0 = bfu(xtile[wave][u0 * 16 + lr]);
            float x1 = bfu(xtile[wave][u1 * 16 + lr]);
            x0 = fmaxf(a_c * x0 + c_c, 0.f);
            x1 = fmaxf(a_c * x1 + c_c, 0.f);
            af.u[h] = packbf(x0, x1);
        }
        const bf16x8 A = af.v;

#pragma unroll
        for (int s = 0; s < 5; s++) {
            f32x4 d0 = __builtin_amdgcn_mfma_f32_16x16x32_bf16(A, Bfrag[s][0], zero, 0, 0, 0);
            f32x4 d1 = __builtin_amdgcn_mfma_f32_16x16x32_bf16(A, Bfrag[s][1], zero, 0, 0, 0);
            f32x4 z0 = __builtin_amdgcn_mfma_f32_16x16x32_bf16(Wfrag[s], packD(d0), zero, 0, 0, 0);
            f32x4 z1 = __builtin_amdgcn_mfma_f32_16x16x32_bf16(Wfrag[s], packD(d1), zero, 0, 0, 0);
            sacc[s] += z0; qacc[s] += z0 * z0;
            if (lr < 9) { sacc[s] += z1; qacc[s] += z1 * z1; }
        }
    }

#pragma unroll
    for (int s = 0; s < 5; s++)
#pragma unroll
        for (int r = 0; r < 4; r++) {
            float sv = sacc[s][r], qv = qacc[s][r];
            sv += __shfl_xor(sv, 1, 64); qv += __shfl_xor(qv, 1, 64);
            sv += __shfl_xor(sv, 2, 64); qv += __shfl_xor(qv, 2, 64);
            sv += __shfl_xor(sv, 4, 64); qv += __shfl_xor(qv, 4, 64);
            sv += __shfl_xor(sv, 8, 64); qv += __shfl_xor(qv, 8, 64);
            if (lr == 0) {
                atomicAdd(&bins[s * 16 + 4 * lg + r], sv);
                atomicAdd(&bins[80 + s * 16 + 4 * lg + r], qv);
            }
        }
    __syncthreads();
    for (int i = tid; i < 160; i += 256) atomicAdd(&stq[l * 160 + i], bins[i]);
}

// ---- K4: fold sub-BN affine into W (W2 = A*W, bf16) and constants into Cagg[64]
__global__ __launch_bounds__(256) void k_finsub(
    const float* __restrict__ stq,    // [3][160]
    const float* __restrict__ Wsub,   // [3][80][16]
    const float* __restrict__ gs, const float* __restrict__ betas,
    unsigned short* __restrict__ W2,  // [3][80][16] bf16 (A-scaled)
    float* __restrict__ Cagg)         // [64]
{
    __shared__ float As[240], Cs[240];
    const int tid = threadIdx.x;
    if (tid < 240) {
        int l = tid / 80, ch = tid - l * 80;
        float m   = stq[l * 160 + ch] * (1.f / CNTF);
        float var = stq[l * 160 + 80 + ch] * (1.f / CNTF) - m * m;
        float a   = gs[l * 80 + ch] * rsqrtf(var + EPS);
        As[tid] = a;
        Cs[tid] = betas[l * 80 + ch] - a * m;
    }
    __syncthreads();
    for (int i = tid; i < 3840; i += 256) {
        int l = i / 1280, r = i - l * 1280, ch = r / 16;
        W2[i] = (unsigned short)f2bf(As[l * 80 + ch] * Wsub[i]);
    }
    if (tid < 64) {
        int sIdx = tid >> 4, o = tid & 15;
        float c = 0.f;
        for (int l = 0; l < 3; l++)
            c += Cs[l * 80 + (sIdx + 1) * 16 + o] + Cs[l * 80 + o];
        Cagg[tid] = c;
    }
}

// ---- K5: fused 3-layer output via MFMA -> bf16 acc [nt][v][64] + final-BN stats.
// Register prefetch (T14): next-nt loads issued right after ds_writes.
__global__ __launch_bounds__(256, 1) void k_out_mfma(
    const unsigned short* __restrict__ xdp,  // [3][nt][u<25][16c]
    const float* __restrict__ PA,            // [3][5][25][25]
    const unsigned short* __restrict__ W2,   // [3][80][16] bf16
    const float* __restrict__ Cagg,          // [64]
    const float* __restrict__ AC,            // [96] down affines
    float* __restrict__ stout,               // [128]
    unsigned short* __restrict__ accb)       // [nt][25][64] bf16
{
    __shared__ unsigned int PAfr[30 * 64 * 4];     // 30 frags x 64 lanes x uint4
    __shared__ unsigned short xtile[4][3][512];
    __shared__ float bins[128];

    const int tid  = threadIdx.x;
    const int wave = tid >> 6, lane = tid & 63;
    const int lr = lane & 15, lg = lane >> 4;

    for (int e = tid; e < 1920; e += 256) {
        int frag = e >> 6, ln = e & 63;
        int l = frag / 10, rem = frag - l * 10;
        int s = rem >> 1, t = rem & 1;
        int elr = ln & 15, elg = ln >> 4;
        int v = t * 16 + elr;
        unsigned int u4[4];
#pragma unroll
        for (int h = 0; h < 4; h++) {
            int u0 = 8 * h + elg, u1 = 8 * h + 4 + elg;
            float f0 = (v < 25 && u0 < 25) ? PA[l * 3125 + (s * 25 + v) * 25 + u0] : 0.f;
            float f1 = (v < 25 && u1 < 25) ? PA[l * 3125 + (s * 25 + v) * 25 + u1] : 0.f;
            u4[h] = packbf(f0, f1);
        }
        *(uint4*)&PAfr[e * 4] = make_uint4(u4[0], u4[1], u4[2], u4[3]);
    }
    for (int i = tid; i < 768; i += 256)
        *(uint4*)&xtile[0][0][i * 8] = make_uint4(0, 0, 0, 0);
    if (tid < 128) bins[tid] = 0.f;

    // GEMM2 A-operand (pre-scaled W): elem r<4 = W2[o=lr][4*lg+r], rest 0
    bf16x8 Wf[3][5];
#pragma unroll
    for (int l = 0; l < 3; l++)
#pragma unroll
        for (int s = 0; s < 5; s++) {
            FRAG f;
            const uint2 w = *(const uint2*)(W2 + ((l * 5 + s) * 16 + lr) * 16 + 4 * lg);
            f.u[0] = w.x; f.u[1] = w.y; f.u[2] = 0u; f.u[3] = 0u;
            Wf[l][s] = f.v;
        }

    float a3[3], c3[3];
#pragma unroll
    for (int l = 0; l < 3; l++) { a3[l] = AC[l * 16 + lr]; c3[l] = AC[48 + l * 16 + lr]; }

    float cagg[4][4];
#pragma unroll
    for (int sI = 0; sI < 4; sI++)
#pragma unroll
        for (int r = 0; r < 4; r++) cagg[sI][r] = Cagg[sI * 16 + 4 * lg + r];

    f32x4 ss[4] = {}, qq[4] = {};
    const f32x4 zero = {};
    __syncthreads();   // PAfr + xtile zero-init visible to all waves

    const int wid = blockIdx.x * 4 + wave;

    // per-lane staging geometry (loop-invariant)
    const int j0 = lane,       l0 = j0 / 50, o0 = j0 - l0 * 50;
    const int j1 = lane + 64,  l1 = j1 / 50, o1 = j1 - l1 * 50;
    const int j2 = lane + 128, l2 = j2 / 50, o2 = j2 - l2 * 50;
    const bool a2 = (j2 < 150);
    const unsigned short* s0 = xdp + (size_t)l0 * XDP_ELEMS + o0 * 8;
    const unsigned short* s1 = xdp + (size_t)l1 * XDP_ELEMS + o1 * 8;
    const unsigned short* s2 = xdp + (size_t)l2 * XDP_ELEMS + o2 * 8;
    unsigned short* d0 = &xtile[wave][l0][o0 * 8];
    unsigned short* d1 = &xtile[wave][l1][o1 * 8];
    unsigned short* d2 = &xtile[wave][l2][o2 * 8];

    uint4 pre0, pre1, pre2 = make_uint4(0, 0, 0, 0);
    {
        size_t b = (size_t)(wid * 4) * 400;
        pre0 = *(const uint4*)(s0 + b);
        pre1 = *(const uint4*)(s1 + b);
        if (a2) pre2 = *(const uint4*)(s2 + b);
    }

    for (int k = 0; k < 4; k++) {
        const int nt = wid * 4 + k;
        *(uint4*)d0 = pre0;
        *(uint4*)d1 = pre1;
        if (a2) *(uint4*)d2 = pre2;
        if (k < 3) {
            size_t b = (size_t)(nt + 1) * 400;
            pre0 = *(const uint4*)(s0 + b);
            pre1 = *(const uint4*)(s1 + b);
            if (a2) pre2 = *(const uint4*)(s2 + b);
        }
        asm volatile("s_waitcnt lgkmcnt(0)" ::: "memory");
        __builtin_amdgcn_sched_barrier(0);

        f32x4 acc0[4] = {}, acc1[4] = {};
#pragma unroll
        for (int l = 0; l < 3; l++) {
            FRAG af;
#pragma unroll
            for (int h = 0; h < 4; h++) {
                int u0 = 8 * h + lg, u1 = 8 * h + 4 + lg;
                float x0 = bfu(xtile[wave][l][u0 * 16 + lr]);
                float x1 = bfu(xtile[wave][l][u1 * 16 + lr]);
                x0 = fmaxf(a3[l] * x0 + c3[l], 0.f);
                x1 = fmaxf(a3[l] * x1 + c3[l], 0.f);
                af.u[h] = packbf(x0, x1);
            }
            const bf16x8 A = af.v;

            f32x4 z0a, z0b;
#pragma unroll
            for (int s = 0; s < 5; s++) {
                FRAG bfA, bfB;
                *(uint4*)bfA.u = *(const uint4*)&PAfr[(((l * 5 + s) * 2 + 0) * 64 + lane) * 4];
                *(uint4*)bfB.u = *(const uint4*)&PAfr[(((l * 5 + s) * 2 + 1) * 64 + lane) * 4];
                f32x4 dA = __builtin_amdgcn_mfma_f32_16x16x32_bf16(A, bfA.v, zero, 0, 0, 0);
                f32x4 dB = __builtin_amdgcn_mfma_f32_16x16x32_bf16(A, bfB.v, zero, 0, 0, 0);
                f32x4 za = __builtin_amdgcn_mfma_f32_16x16x32_bf16(Wf[l][s], packD(dA), zero, 0, 0, 0);
                f32x4 zb = __builtin_amdgcn_mfma_f32_16x16x32_bf16(Wf[l][s], packD(dB), zero, 0, 0, 0);
                if (s == 0) { z0a = za; z0b = zb; }
                else {
                    acc0[s - 1] += za + z0a;
                    acc1[s - 1] += zb + z0b;
                }
            }
        }

        // bf16 acc write: [nt][v][64ch]; each (nt,v) row = 128B line.
        unsigned short* ab0 = accb + ((size_t)nt * 25 + lr) * 64;
        unsigned short* ab1 = accb + ((size_t)nt * 25 + 16 + lr) * 64;
#pragma unroll
        for (int sI = 0; sI < 4; sI++) {
            float v00 = acc0[sI][0] + cagg[sI][0];
            float v01 = acc0[sI][1] + cagg[sI][1];
            float v02 = acc0[sI][2] + cagg[sI][2];
            float v03 = acc0[sI][3] + cagg[sI][3];
            *(uint2*)(ab0 + sI * 16 + 4 * lg) =
                make_uint2(packbf(v00, v01), packbf(v02, v03));
            float v10 = acc1[sI][0] + cagg[sI][0];
            float v11 = acc1[sI][1] + cagg[sI][1];
            float v12 = acc1[sI][2] + cagg[sI][2];
            float v13 = acc1[sI][3] + cagg[sI][3];
            float u0 = (lr < 9) ? v10 : 0.f, u1 = (lr < 9) ? v11 : 0.f;
            float u2 = (lr < 9) ? v12 : 0.f, u3 = (lr < 9) ? v13 : 0.f;
            if (lr < 9)
                *(uint2*)(ab1 + sI * 16 + 4 * lg) =
                    make_uint2(packbf(v10, v11), packbf(v12, v13));
            ss[sI][0] += v00 + u0; qq[sI][0] += v00 * v00 + u0 * u0;
            ss[sI][1] += v01 + u1; qq[sI][1] += v01 * v01 + u1 * u1;
            ss[sI][2] += v02 + u2; qq[sI][2] += v02 * v02 + u2 * u2;
            ss[sI][3] += v03 + u3; qq[sI][3] += v03 * v03 + u3 * u3;
        }
    }

#pragma unroll
    for (int sI = 0; sI < 4; sI++)
#pragma unroll
        for (int r = 0; r < 4; r++) {
            float sv = ss[sI][r], qv = qq[sI][r];
            sv += __shfl_xor(sv, 1, 64); qv += __shfl_xor(qv, 1, 64);
            sv += __shfl_xor(sv, 2, 64); qv += __shfl_xor(qv, 2, 64);
            sv += __shfl_xor(sv, 4, 64); qv += __shfl_xor(qv, 4, 64);
            sv += __shfl_xor(sv, 8, 64); qv += __shfl_xor(qv, 8, 64);
            if (lr == 0) {
                atomicAdd(&bins[sI * 16 + 4 * lg + r], sv);
                atomicAdd(&bins[64 + sI * 16 + 4 * lg + r], qv);
            }
        }
    __syncthreads();
    if (tid < 128) atomicAdd(&stout[tid], bins[tid]);
}

// ---- K6: out = relu(bn(acc) + x), coalesced via LDS transpose (8 nt/block)
__global__ __launch_bounds__(256, 2) void k_final2(
    const unsigned short* __restrict__ accb, const float* __restrict__ x,
    const float* __restrict__ go, const float* __restrict__ bo,
    const float* __restrict__ stout, float* __restrict__ out)
{
    __shared__ float ao[64], co[64];
    __shared__ float tile[32][208];
    const int tid = threadIdx.x;
    if (tid < 64) {
        float m   = stout[tid] * (1.f / CNTF);
        float var = stout[64 + tid] * (1.f / CNTF) - m * m;
        float a   = go[tid] * rsqrtf(var + EPS);
        ao[tid] = a; co[tid] = bo[tid] - m * a;
    }

    const int nt0 = blockIdx.x * 8, n = nt0 >> 7, t0 = nt0 & 127;
    const int pp = tid / 25, v = tid - pp * 25;
    const unsigned short* arow = accb + ((size_t)(nt0 + pp) * 25 + v) * 64;

#pragma unroll
    for (int h = 0; h < 2; h++) {
        __syncthreads();   // ao/co ready (h=0) / prev-half tile reads done (h=1)
        if (tid < 200) {
#pragma unroll
            for (int j = 0; j < 4; j++) {
                uint4 w = *(const uint4*)(arow + h * 32 + j * 8);
                const int cb = h * 32 + j * 8;
                tile[j*8+0][tid] = ao[cb+0] * bfu(w.x & 0xffffu) + co[cb+0];
                tile[j*8+1][tid] = ao[cb+1] * bfu(w.x >> 16)     + co[cb+1];
                tile[j*8+2][tid] = ao[cb+2] * bfu(w.y & 0xffffu) + co[cb+2];
                tile[j*8+3][tid] = ao[cb+3] * bfu(w.y >> 16)     + co[cb+3];
                tile[j*8+4][tid] = ao[cb+4] * bfu(w.z & 0xffffu) + co[cb+4];
                tile[j*8+5][tid] = ao[cb+5] * bfu(w.z >> 16)     + co[cb+5];
                tile[j*8+6][tid] = ao[cb+6] * bfu(w.w & 0xffffu) + co[cb+6];
                tile[j*8+7][tid] = ao[cb+7] * bfu(w.w >> 16)     + co[cb+7];
            }
        }
        __syncthreads();
        for (int i = tid; i < 6400; i += 256) {
            int kk = i / 200, p = i - kk * 200;
            int adr = n * 204800 + (h * 32 + kk) * 3200 + t0 * 25 + p;
            out[adr] = fmaxf(tile[kk][p] + x[adr], 0.f);
        }
    }
}

extern "C" void kernel_launch(void* const* d_in, const int* in_sizes, int n_in,
                              void* d_out, int out_size, void* d_ws, size_t ws_size,
                              hipStream_t stream)
{
    const float* x     = (const float*)d_in[0];
    const float* PA    = (const float*)d_in[1];
    const float* Wd    = (const float*)d_in[2];
    const float* gd    = (const float*)d_in[4];
    const float* betad = (const float*)d_in[5];
    const float* Wsub  = (const float*)d_in[6];
    const float* gsub  = (const float*)d_in[8];
    const float* betas = (const float*)d_in[9];
    const float* gout  = (const float*)d_in[10];
    const float* betao = (const float*)d_in[11];
    float* out = (float*)d_out;

    unsigned short* xdp  = (unsigned short*)d_ws;            // 39.3 MB
    unsigned short* accb = xdp + (size_t)3 * XDP_ELEMS;      // 52.4 MB bf16
    float* st    = (float*)(accb + (size_t)ACC_ELEMS);
    float* AC    = st + 96;
    float* stq   = AC + 96;       // [3][160]
    float* stout = stq + 480;     // [128]
    float* Wtg   = stout + 128;   // [64][48]
    float* Cagg  = Wtg + 3072;    // [64]
    unsigned short* W2 = (unsigned short*)(Cagg + 64);  // [3][80][16] bf16

    hipMemsetAsync(st, 0, (96 + 96 + 480 + 128) * sizeof(float), stream);

    k_prep   <<<1,   256, 0, stream>>>(Wd, Wtg);
    k_down3  <<<800, 256, 0, stream>>>(x, Wtg, xdp, st);
    k_findown<<<1,    64, 0, stream>>>(st, gd, betad, AC);

    k_zstats3 <<<3072, 256, 0, stream>>>(xdp, PA, Wsub, AC, stq);
    k_finsub  <<<1,    256, 0, stream>>>(stq, Wsub, gsub, betas, W2, Cagg);
    k_out_mfma<<<1024, 256, 0, stream>>>(xdp, PA, W2, Cagg, AC, stout, accb);
    k_final2  <<<2048, 256, 0, stream>>>(accb, x, gout, betao, stout, out);
}

// Round 16
// 361.281 us; speedup vs baseline: 1.3357x; 1.0623x over previous
//
#include <hip/hip_runtime.h>
#include <hip/hip_bf16.h>

#define EPS  1e-5f
#define CNTF 409600.0f            // N*T*V
#define XDP_ELEMS 6553600         // per layer: 16384 nt * 400, layout [nt][u][16o]
#define ACC_ELEMS 26214400        // 16384 nt * 25 v * 64 ch (bf16)

typedef short bf16x8 __attribute__((ext_vector_type(8)));
typedef float f32x4  __attribute__((ext_vector_type(4)));

union FRAG { unsigned int u[4]; bf16x8 v; };

__device__ __forceinline__ float wave_sum(float v) {
#pragma unroll
    for (int off = 32; off > 0; off >>= 1)
        v += __shfl_down(v, off, 64);
    return v;
}

__device__ __forceinline__ float bfu(unsigned int u16) {
    union { unsigned int i; float f; } x;
    x.i = u16 << 16;
    return x.f;
}
// scalar casts -> compiler fuses pairs into v_cvt_pk_bf16_f32 (T12/m240)
__device__ __forceinline__ unsigned short f2bfu(float f) {
    union { __hip_bfloat16 h; unsigned short u; } c;
    c.h = __float2bfloat16(f);
    return c.u;
}
__device__ __forceinline__ unsigned int packbf(float a, float b) {
    return (unsigned int)f2bfu(a) | ((unsigned int)f2bfu(b) << 16);
}

// Pack MFMA1's D-register directly as the second MFMA's B operand.
// Bijection for GEMM2: k-slot (lg, elem r<4) <-> c = 4*lg + r; elems 4..7 pad(0).
__device__ __forceinline__ bf16x8 packD(const f32x4 d) {
    FRAG f;
    f.u[0] = packbf(d[0], d[1]);
    f.u[1] = packbf(d[2], d[3]);
    f.u[2] = 0u;
    f.u[3] = 0u;
    return f.v;
}

// ---- K0: transpose W_down into [c][48] so k_down3 can scalar-load it
__global__ __launch_bounds__(256) void k_prep(const float* __restrict__ Wd,
                                              float* __restrict__ Wtg)
{
    for (int j = threadIdx.x; j < 3072; j += 256) {
        int c = j / 48, k = j - c * 48;
        int l = k / 16, o = k - l * 16;
        Wtg[j] = Wd[l * 1024 + o * 64 + c];
    }
}

// ---- K1: conv_down all 3 layers (bias cancels in BN), bf16 xd + stats.
__global__ __launch_bounds__(256) void k_down3(
    const float* __restrict__ x, const float* __restrict__ Wtg,
    unsigned short* __restrict__ xdp, float* __restrict__ st /*96*/)
{
    __shared__ float bins[96];
    const int tid = threadIdx.x;
    if (tid < 96) bins[tid] = 0.f;
    __syncthreads();

    const int base = (blockIdx.x * 256 + tid) * 2;
    const int n = base / 3200, pb = base - n * 3200;
    const float* xb = x + n * 204800 + pb;

    float acc0[48], acc1[48];
#pragma unroll
    for (int k = 0; k < 48; k++) { acc0[k] = 0.f; acc1[k] = 0.f; }

    for (int c = 0; c < 64; c++) {
        float2 xv = *(const float2*)&xb[c * 3200];
        const float4* wr = (const float4*)(Wtg + c * 48);   // uniform -> s_load
#pragma unroll
        for (int q = 0; q < 12; q++) {
            float4 w = wr[q];
            acc0[4*q+0] += w.x * xv.x;  acc1[4*q+0] += w.x * xv.y;
            acc0[4*q+1] += w.y * xv.x;  acc1[4*q+1] += w.y * xv.y;
            acc0[4*q+2] += w.z * xv.x;  acc1[4*q+2] += w.z * xv.y;
            acc0[4*q+3] += w.w * xv.x;  acc1[4*q+3] += w.w * xv.y;
        }
    }
#pragma unroll
    for (int l = 0; l < 3; l++) {
        unsigned int pk0[8], pk1[8];
#pragma unroll
        for (int h = 0; h < 8; h++) {
            pk0[h] = packbf(acc0[l*16 + 2*h], acc0[l*16 + 2*h + 1]);
            pk1[h] = packbf(acc1[l*16 + 2*h], acc1[l*16 + 2*h + 1]);
        }
        uint4* dst = (uint4*)(xdp + (size_t)l * XDP_ELEMS + (size_t)base * 16);
        dst[0] = make_uint4(pk0[0], pk0[1], pk0[2], pk0[3]);
        dst[1] = make_uint4(pk0[4], pk0[5], pk0[6], pk0[7]);
        dst[2] = make_uint4(pk1[0], pk1[1], pk1[2], pk1[3]);
        dst[3] = make_uint4(pk1[4], pk1[5], pk1[6], pk1[7]);
    }

    const int lane = tid & 63;
#pragma unroll
    for (int k = 0; k < 48; k++) {
        float sv = wave_sum(acc0[k] + acc1[k]);
        float qv = wave_sum(acc0[k] * acc0[k] + acc1[k] * acc1[k]);
        if (lane == 0) { atomicAdd(&bins[k], sv); atomicAdd(&bins[48 + k], qv); }
    }
    __syncthreads();
    if (tid < 96) atomicAdd(&st[tid], bins[tid]);
}

// ---- K2: finalize down affines
__global__ __launch_bounds__(64) void k_findown(
    const float* __restrict__ st, const float* __restrict__ gd,
    const float* __restrict__ betad, float* __restrict__ AC)
{
    int t = threadIdx.x;
    if (t < 48) {
        float m   = st[t] * (1.f / CNTF);
        float var = st[48 + t] * (1.f / CNTF) - m * m;
        float a   = gd[t] * rsqrtf(var + EPS);
        AC[t]      = a;
        AC[48 + t] = betad[t] - a * m;
    }
}

// ---- K3: ALL-layer z stats via MFMA (fused; layer = blockIdx>>9).
// 8 nt per wave (prologue amortized); (256,2): cap 128 VGPR -> 4 waves/SIMD.
__global__ __launch_bounds__(256, 2) void k_zstats3(
    const unsigned short* __restrict__ xdp,  // [3][nt][u<25][16c] bf16
    const float* __restrict__ PA,            // [3][5][25][25]
    const float* __restrict__ Wsub,          // [3][80][16]
    const float* __restrict__ AC,            // [96]
    float* __restrict__ stq)                 // [3][160]
{
    __shared__ unsigned short xtile[4][512];
    __shared__ float bins[160];

    const int l   = blockIdx.x >> 9;
    const int blk = blockIdx.x & 511;
    const unsigned short* xd = xdp + (size_t)l * XDP_ELEMS;
    const float* PAl = PA + l * 3125;
    const float* Wsl = Wsub + l * 1280;

    const int tid  = threadIdx.x;
    const int wave = tid >> 6, lane = tid & 63;
    const int lr = lane & 15, lg = lane >> 4;

    *(uint4*)&xtile[tid >> 6][(tid & 63) * 8] = make_uint4(0, 0, 0, 0);
    for (int i = tid; i < 160; i += 256) bins[i] = 0.f;
    __syncthreads();

    bf16x8 Bfrag[5][2];
#pragma unroll
    for (int s = 0; s < 5; s++)
#pragma unroll
        for (int t = 0; t < 2; t++) {
            FRAG f;
            const int v = t * 16 + lr;
#pragma unroll
            for (int h = 0; h < 4; h++) {
                int u0 = 8 * h + lg, u1 = 8 * h + 4 + lg;
                float f0 = (v < 25 && u0 < 25) ? PAl[(s * 25 + v) * 25 + u0] : 0.f;
                float f1 = (v < 25 && u1 < 25) ? PAl[(s * 25 + v) * 25 + u1] : 0.f;
                f.u[h] = packbf(f0, f1);
            }
            Bfrag[s][t] = f.v;
        }

    // GEMM2 A-operand (W): elem r<4 = W[o=lr][c=4*lg+r], elems 4..7 = 0
    bf16x8 Wfrag[5];
#pragma unroll
    for (int s = 0; s < 5; s++) {
        FRAG f;
        const float* wr = Wsl + (s * 16 + lr) * 16 + 4 * lg;
        f.u[0] = packbf(wr[0], wr[1]);
        f.u[1] = packbf(wr[2], wr[3]);
        f.u[2] = 0u; f.u[3] = 0u;
        Wfrag[s] = f.v;
    }

    const float a_c = AC[l * 16 + lr], c_c = AC[48 + l * 16 + lr];

    f32x4 sacc[5] = {};
    f32x4 qacc[5] = {};
    const f32x4 zero = {};

    const int wid = blk * 4 + wave;
    const unsigned short* sbase = xd + lane * 8;   // + nt*400
    unsigned short* dstp = &xtile[wave][lane * 8];
    uint4 pre = make_uint4(0, 0, 0, 0);
    if (lane < 50) pre = *(const uint4*)(sbase + (size_t)(wid * 8) * 400);

    for (int k = 0; k < 8; k++) {
        if (lane < 50) *(uint4*)dstp = pre;
        if (k < 7 && lane < 50)
            pre = *(const uint4*)(sbase + (size_t)(wid * 8 + k + 1) * 400);
        asm volatile("s_waitcnt lgkmcnt(0)" ::: "memory");
        __builtin_amdgcn_sched_barrier(0);

        FRAG af;
#pragma unroll
        for (int h = 0; h < 4; h++) {
            int u0 = 8 * h + lg, u1 = 8 * h + 4 + lg;
            float x0 = bfu(xtile[wave][u0 * 16 + lr]);
            float x1 = bfu(xtile[wave][u1 * 16 + lr]);
            x0 = fmaxf(a_c * x0 + c_c, 0.f);
            x1 = fmaxf(a_c * x1 + c_c, 0.f);
            af.u[h] = packbf(x0, x1);
        }
        const bf16x8 A = af.v;

#pragma unroll
        for (int s = 0; s < 5; s++) {
            f32x4 d0 = __builtin_amdgcn_mfma_f32_16x16x32_bf16(A, Bfrag[s][0], zero, 0, 0, 0);
            f32x4 d1 = __builtin_amdgcn_mfma_f32_16x16x32_bf16(A, Bfrag[s][1], zero, 0, 0, 0);
            f32x4 z0 = __builtin_amdgcn_mfma_f32_16x16x32_bf16(Wfrag[s], packD(d0), zero, 0, 0, 0);
            f32x4 z1 = __builtin_amdgcn_mfma_f32_16x16x32_bf16(Wfrag[s], packD(d1), zero, 0, 0, 0);
            sacc[s] += z0; qacc[s] += z0 * z0;
            if (lr < 9) { sacc[s] += z1; qacc[s] += z1 * z1; }
        }
    }

#pragma unroll
    for (int s = 0; s < 5; s++)
#pragma unroll
        for (int r = 0; r < 4; r++) {
            float sv = sacc[s][r], qv = qacc[s][r];
            sv += __shfl_xor(sv, 1, 64); qv += __shfl_xor(qv, 1, 64);
            sv += __shfl_xor(sv, 2, 64); qv += __shfl_xor(qv, 2, 64);
            sv += __shfl_xor(sv, 4, 64); qv += __shfl_xor(qv, 4, 64);
            sv += __shfl_xor(sv, 8, 64); qv += __shfl_xor(qv, 8, 64);
            if (lr == 0) {
                atomicAdd(&bins[s * 16 + 4 * lg + r], sv);
                atomicAdd(&bins[80 + s * 16 + 4 * lg + r], qv);
            }
        }
    __syncthreads();
    for (int i = tid; i < 160; i += 256) atomicAdd(&stq[l * 160 + i], bins[i]);
}

// ---- K4: fold sub-BN affine into W (W2 = A*W, bf16) and constants into Cagg[64]
__global__ __launch_bounds__(256) void k_finsub(
    const float* __restrict__ stq,    // [3][160]
    const float* __restrict__ Wsub,   // [3][80][16]
    const float* __restrict__ gs, const float* __restrict__ betas,
    unsigned short* __restrict__ W2,  // [3][80][16] bf16 (A-scaled)
    float* __restrict__ Cagg)         // [64]
{
    __shared__ float As[240], Cs[240];
    const int tid = threadIdx.x;
    if (tid < 240) {
        int l = tid / 80, ch = tid - l * 80;
        float m   = stq[l * 160 + ch] * (1.f / CNTF);
        float var = stq[l * 160 + 80 + ch] * (1.f / CNTF) - m * m;
        float a   = gs[l * 80 + ch] * rsqrtf(var + EPS);
        As[tid] = a;
        Cs[tid] = betas[l * 80 + ch] - a * m;
    }
    __syncthreads();
    for (int i = tid; i < 3840; i += 256) {
        int l = i / 1280, r = i - l * 1280, ch = r / 16;
        W2[i] = f2bfu(As[l * 80 + ch] * Wsub[i]);
    }
    if (tid < 64) {
        int sIdx = tid >> 4, o = tid & 15;
        float c = 0.f;
        for (int l = 0; l < 3; l++)
            c += Cs[l * 80 + (sIdx + 1) * 16 + o] + Cs[l * 80 + o];
        Cagg[tid] = c;
    }
}

// ---- K5: fused 3-layer output via MFMA -> bf16 acc [nt][v][64] + final-BN stats.
__global__ __launch_bounds__(256, 1) void k_out_mfma(
    const unsigned short* __restrict__ xdp,  // [3][nt][u<25][16c]
    const float* __restrict__ PA,            // [3][5][25][25]
    const unsigned short* __restrict__ W2,   // [3][80][16] bf16
    const float* __restrict__ Cagg,          // [64]
    const float* __restrict__ AC,            // [96] down affines
    float* __restrict__ stout,               // [128]
    unsigned short* __restrict__ accb)       // [nt][25][64] bf16
{
    __shared__ unsigned int PAfr[30 * 64 * 4];     // 30 frags x 64 lanes x uint4
    __shared__ unsigned short xtile[4][3][512];
    __shared__ float bins[128];

    const int tid  = threadIdx.x;
    const int wave = tid >> 6, lane = tid & 63;
    const int lr = lane & 15, lg = lane >> 4;

    for (int e = tid; e < 1920; e += 256) {
        int frag = e >> 6, ln = e & 63;
        int l = frag / 10, rem = frag - l * 10;
        int s = rem >> 1, t = rem & 1;
        int elr = ln & 15, elg = ln >> 4;
        int v = t * 16 + elr;
        unsigned int u4[4];
#pragma unroll
        for (int h = 0; h < 4; h++) {
            int u0 = 8 * h + elg, u1 = 8 * h + 4 + elg;
            float f0 = (v < 25 && u0 < 25) ? PA[l * 3125 + (s * 25 + v) * 25 + u0] : 0.f;
            float f1 = (v < 25 && u1 < 25) ? PA[l * 3125 + (s * 25 + v) * 25 + u1] : 0.f;
            u4[h] = packbf(f0, f1);
        }
        *(uint4*)&PAfr[e * 4] = make_uint4(u4[0], u4[1], u4[2], u4[3]);
    }
    for (int i = tid; i < 768; i += 256)
        *(uint4*)&xtile[0][0][i * 8] = make_uint4(0, 0, 0, 0);
    if (tid < 128) bins[tid] = 0.f;

    // GEMM2 A-operand (pre-scaled W): elem r<4 = W2[o=lr][4*lg+r], rest 0
    bf16x8 Wf[3][5];
#pragma unroll
    for (int l = 0; l < 3; l++)
#pragma unroll
        for (int s = 0; s < 5; s++) {
            FRAG f;
            const uint2 w = *(const uint2*)(W2 + ((l * 5 + s) * 16 + lr) * 16 + 4 * lg);
            f.u[0] = w.x; f.u[1] = w.y; f.u[2] = 0u; f.u[3] = 0u;
            Wf[l][s] = f.v;
        }

    float a3[3], c3[3];
#pragma unroll
    for (int l = 0; l < 3; l++) { a3[l] = AC[l * 16 + lr]; c3[l] = AC[48 + l * 16 + lr]; }

    float cagg[4][4];
#pragma unroll
    for (int sI = 0; sI < 4; sI++)
#pragma unroll
        for (int r = 0; r < 4; r++) cagg[sI][r] = Cagg[sI * 16 + 4 * lg + r];

    f32x4 ss[4] = {}, qq[4] = {};
    const f32x4 zero = {};
    __syncthreads();   // PAfr + xtile zero-init visible to all waves

    const int wid = blockIdx.x * 4 + wave;

    // per-lane staging geometry (loop-invariant)
    const int j0 = lane,       l0 = j0 / 50, o0 = j0 - l0 * 50;
    const int j1 = lane + 64,  l1 = j1 / 50, o1 = j1 - l1 * 50;
    const int j2 = lane + 128, l2 = j2 / 50, o2 = j2 - l2 * 50;
    const bool a2 = (j2 < 150);
    const unsigned short* s0 = xdp + (size_t)l0 * XDP_ELEMS + o0 * 8;
    const unsigned short* s1 = xdp + (size_t)l1 * XDP_ELEMS + o1 * 8;
    const unsigned short* s2 = xdp + (size_t)l2 * XDP_ELEMS + o2 * 8;
    unsigned short* d0 = &xtile[wave][l0][o0 * 8];
    unsigned short* d1 = &xtile[wave][l1][o1 * 8];
    unsigned short* d2 = &xtile[wave][l2][o2 * 8];

    uint4 pre0, pre1, pre2 = make_uint4(0, 0, 0, 0);
    {
        size_t b = (size_t)(wid * 4) * 400;
        pre0 = *(const uint4*)(s0 + b);
        pre1 = *(const uint4*)(s1 + b);
        if (a2) pre2 = *(const uint4*)(s2 + b);
    }

    for (int k = 0; k < 4; k++) {
        const int nt = wid * 4 + k;
        *(uint4*)d0 = pre0;
        *(uint4*)d1 = pre1;
        if (a2) *(uint4*)d2 = pre2;
        if (k < 3) {
            size_t b = (size_t)(nt + 1) * 400;
            pre0 = *(const uint4*)(s0 + b);
            pre1 = *(const uint4*)(s1 + b);
            if (a2) pre2 = *(const uint4*)(s2 + b);
        }
        asm volatile("s_waitcnt lgkmcnt(0)" ::: "memory");
        __builtin_amdgcn_sched_barrier(0);

        f32x4 acc0[4] = {}, acc1[4] = {};
#pragma unroll
        for (int l = 0; l < 3; l++) {
            FRAG af;
#pragma unroll
            for (int h = 0; h < 4; h++) {
                int u0 = 8 * h + lg, u1 = 8 * h + 4 + lg;
                float x0 = bfu(xtile[wave][l][u0 * 16 + lr]);
                float x1 = bfu(xtile[wave][l][u1 * 16 + lr]);
                x0 = fmaxf(a3[l] * x0 + c3[l], 0.f);
                x1 = fmaxf(a3[l] * x1 + c3[l], 0.f);
                af.u[h] = packbf(x0, x1);
            }
            const bf16x8 A = af.v;

            f32x4 z0a, z0b;
#pragma unroll
            for (int s = 0; s < 5; s++) {
                FRAG bfA, bfB;
                *(uint4*)bfA.u = *(const uint4*)&PAfr[(((l * 5 + s) * 2 + 0) * 64 + lane) * 4];
                *(uint4*)bfB.u = *(const uint4*)&PAfr[(((l * 5 + s) * 2 + 1) * 64 + lane) * 4];
                f32x4 dA = __builtin_amdgcn_mfma_f32_16x16x32_bf16(A, bfA.v, zero, 0, 0, 0);
                f32x4 dB = __builtin_amdgcn_mfma_f32_16x16x32_bf16(A, bfB.v, zero, 0, 0, 0);
                f32x4 za = __builtin_amdgcn_mfma_f32_16x16x32_bf16(Wf[l][s], packD(dA), zero, 0, 0, 0);
                f32x4 zb = __builtin_amdgcn_mfma_f32_16x16x32_bf16(Wf[l][s], packD(dB), zero, 0, 0, 0);
                if (s == 0) { z0a = za; z0b = zb; }
                else {
                    acc0[s - 1] += za + z0a;
                    acc1[s - 1] += zb + z0b;
                }
            }
        }

        // bf16 acc write: [nt][v][64ch]; each (nt,v) row = 128B line.
        unsigned short* ab0 = accb + ((size_t)nt * 25 + lr) * 64;
        unsigned short* ab1 = accb + ((size_t)nt * 25 + 16 + lr) * 64;
#pragma unroll
        for (int sI = 0; sI < 4; sI++) {
            float v00 = acc0[sI][0] + cagg[sI][0];
            float v01 = acc0[sI][1] + cagg[sI][1];
            float v02 = acc0[sI][2] + cagg[sI][2];
            float v03 = acc0[sI][3] + cagg[sI][3];
            *(uint2*)(ab0 + sI * 16 + 4 * lg) =
                make_uint2(packbf(v00, v01), packbf(v02, v03));
            float v10 = acc1[sI][0] + cagg[sI][0];
            float v11 = acc1[sI][1] + cagg[sI][1];
            float v12 = acc1[sI][2] + cagg[sI][2];
            float v13 = acc1[sI][3] + cagg[sI][3];
            float u0 = (lr < 9) ? v10 : 0.f, u1 = (lr < 9) ? v11 : 0.f;
            float u2 = (lr < 9) ? v12 : 0.f, u3 = (lr < 9) ? v13 : 0.f;
            if (lr < 9)
                *(uint2*)(ab1 + sI * 16 + 4 * lg) =
                    make_uint2(packbf(v10, v11), packbf(v12, v13));
            ss[sI][0] += v00 + u0; qq[sI][0] += v00 * v00 + u0 * u0;
            ss[sI][1] += v01 + u1; qq[sI][1] += v01 * v01 + u1 * u1;
            ss[sI][2] += v02 + u2; qq[sI][2] += v02 * v02 + u2 * u2;
            ss[sI][3] += v03 + u3; qq[sI][3] += v03 * v03 + u3 * u3;
        }
    }

#pragma unroll
    for (int sI = 0; sI < 4; sI++)
#pragma unroll
        for (int r = 0; r < 4; r++) {
            float sv = ss[sI][r], qv = qq[sI][r];
            sv += __shfl_xor(sv, 1, 64); qv += __shfl_xor(qv, 1, 64);
            sv += __shfl_xor(sv, 2, 64); qv += __shfl_xor(qv, 2, 64);
            sv += __shfl_xor(sv, 4, 64); qv += __shfl_xor(qv, 4, 64);
            sv += __shfl_xor(sv, 8, 64); qv += __shfl_xor(qv, 8, 64);
            if (lr == 0) {
                atomicAdd(&bins[sI * 16 + 4 * lg + r], sv);
                atomicAdd(&bins[64 + sI * 16 + 4 * lg + r], qv);
            }
        }
    __syncthreads();
    if (tid < 128) atomicAdd(&stout[tid], bins[tid]);
}

// ---- K6: out = relu(bn(acc) + x), coalesced via LDS transpose (8 nt/block)
__global__ __launch_bounds__(256, 2) void k_final2(
    const unsigned short* __restrict__ accb, const float* __restrict__ x,
    const float* __restrict__ go, const float* __restrict__ bo,
    const float* __restrict__ stout, float* __restrict__ out)
{
    __shared__ float ao[64], co[64];
    __shared__ float tile[32][208];
    const int tid = threadIdx.x;
    if (tid < 64) {
        float m   = stout[tid] * (1.f / CNTF);
        float var = stout[64 + tid] * (1.f / CNTF) - m * m;
        float a   = go[tid] * rsqrtf(var + EPS);
        ao[tid] = a; co[tid] = bo[tid] - m * a;
    }

    const int nt0 = blockIdx.x * 8, n = nt0 >> 7, t0 = nt0 & 127;
    const int pp = tid / 25, v = tid - pp * 25;
    const unsigned short* arow = accb + ((size_t)(nt0 + pp) * 25 + v) * 64;

#pragma unroll
    for (int h = 0; h < 2; h++) {
        __syncthreads();   // ao/co ready (h=0) / prev-half tile reads done (h=1)
        if (tid < 200) {
#pragma unroll
            for (int j = 0; j < 4; j++) {
                uint4 w = *(const uint4*)(arow + h * 32 + j * 8);
                const int cb = h * 32 + j * 8;
                tile[j*8+0][tid] = ao[cb+0] * bfu(w.x & 0xffffu) + co[cb+0];
                tile[j*8+1][tid] = ao[cb+1] * bfu(w.x >> 16)     + co[cb+1];
                tile[j*8+2][tid] = ao[cb+2] * bfu(w.y & 0xffffu) + co[cb+2];
                tile[j*8+3][tid] = ao[cb+3] * bfu(w.y >> 16)     + co[cb+3];
                tile[j*8+4][tid] = ao[cb+4] * bfu(w.z & 0xffffu) + co[cb+4];
                tile[j*8+5][tid] = ao[cb+5] * bfu(w.z >> 16)     + co[cb+5];
                tile[j*8+6][tid] = ao[cb+6] * bfu(w.w & 0xffffu) + co[cb+6];
                tile[j*8+7][tid] = ao[cb+7] * bfu(w.w >> 16)     + co[cb+7];
            }
        }
        __syncthreads();
        for (int i = tid; i < 6400; i += 256) {
            int kk = i / 200, p = i - kk * 200;
            int adr = n * 204800 + (h * 32 + kk) * 3200 + t0 * 25 + p;
            out[adr] = fmaxf(tile[kk][p] + x[adr], 0.f);
        }
    }
}

extern "C" void kernel_launch(void* const* d_in, const int* in_sizes, int n_in,
                              void* d_out, int out_size, void* d_ws, size_t ws_size,
                              hipStream_t stream)
{
    const float* x     = (const float*)d_in[0];
    const float* PA    = (const float*)d_in[1];
    const float* Wd    = (const float*)d_in[2];
    const float* gd    = (const float*)d_in[4];
    const float* betad = (const float*)d_in[5];
    const float* Wsub  = (const float*)d_in[6];
    const float* gsub  = (const float*)d_in[8];
    const float* betas = (const float*)d_in[9];
    const float* gout  = (const float*)d_in[10];
    const float* betao = (const float*)d_in[11];
    float* out = (float*)d_out;

    unsigned short* xdp  = (unsigned short*)d_ws;            // 39.3 MB
    unsigned short* accb = xdp + (size_t)3 * XDP_ELEMS;      // 52.4 MB bf16
    float* st    = (float*)(accb + (size_t)ACC_ELEMS);
    float* AC    = st + 96;
    float* stq   = AC + 96;       // [3][160]
    float* stout = stq + 480;     // [128]
    float* Wtg   = stout + 128;   // [64][48]
    float* Cagg  = Wtg + 3072;    // [64]
    unsigned short* W2 = (unsigned short*)(Cagg + 64);  // [3][80][16] bf16

    hipMemsetAsync(st, 0, (96 + 96 + 480 + 128) * sizeof(float), stream);

    k_prep   <<<1,   256, 0, stream>>>(Wd, Wtg);
    k_down3  <<<800, 256, 0, stream>>>(x, Wtg, xdp, st);
    k_findown<<<1,    64, 0, stream>>>(st, gd, betad, AC);

    k_zstats3 <<<1536, 256, 0, stream>>>(xdp, PA, Wsub, AC, stq);
    k_finsub  <<<1,    256, 0, stream>>>(stq, Wsub, gsub, betas, W2, Cagg);
    k_out_mfma<<<1024, 256, 0, stream>>>(xdp, PA, W2, Cagg, AC, stout, accb);
    k_final2  <<<2048, 256, 0, stream>>>(accb, x, gout, betao, stout, out);
}

// Round 17
// 293.912 us; speedup vs baseline: 1.6419x; 1.2292x over previous
//
#include <hip/hip_runtime.h>
#include <hip/hip_bf16.h>

#define EPS  1e-5f
#define CNTF 409600.0f            // N*T*V
#define XDP_ELEMS 6553600         // per layer: 16384 nt * 400, layout [nt][u][16o]
#define ACC_ELEMS 26214400        // 16384 nt * 25 v * 64 ch (bf16)

typedef short bf16x8 __attribute__((ext_vector_type(8)));
typedef float f32x4  __attribute__((ext_vector_type(4)));

union FRAG { unsigned int u[4]; bf16x8 v; };

__device__ __forceinline__ float wave_sum(float v) {
#pragma unroll
    for (int off = 32; off > 0; off >>= 1)
        v += __shfl_down(v, off, 64);
    return v;
}

__device__ __forceinline__ float bfu(unsigned int u16) {
    union { unsigned int i; float f; } x;
    x.i = u16 << 16;
    return x.f;
}
// scalar casts -> compiler fuses pairs into v_cvt_pk_bf16_f32 (T12/m240)
__device__ __forceinline__ unsigned short f2bfu(float f) {
    union { __hip_bfloat16 h; unsigned short u; } c;
    c.h = __float2bfloat16(f);
    return c.u;
}
__device__ __forceinline__ unsigned int packbf(float a, float b) {
    return (unsigned int)f2bfu(a) | ((unsigned int)f2bfu(b) << 16);
}

// Pack MFMA1's D-register directly as the second MFMA's B operand.
// Bijection for GEMM2: k-slot (lg, elem r<4) <-> c = 4*lg + r; elems 4..7 pad(0).
__device__ __forceinline__ bf16x8 packD(const f32x4 d) {
    FRAG f;
    f.u[0] = packbf(d[0], d[1]);
    f.u[1] = packbf(d[2], d[3]);
    f.u[2] = 0u;
    f.u[3] = 0u;
    return f.v;
}

// ---- K0: transpose W_down into [c][48] so k_down3 can scalar-load it
__global__ __launch_bounds__(256) void k_prep(const float* __restrict__ Wd,
                                              float* __restrict__ Wtg)
{
    for (int j = threadIdx.x; j < 3072; j += 256) {
        int c = j / 48, k = j - c * 48;
        int l = k / 16, o = k - l * 16;
        Wtg[j] = Wd[l * 1024 + o * 64 + c];
    }
}

// ---- K1: conv_down all 3 layers (bias cancels in BN), bf16 xd + stats.
__global__ __launch_bounds__(256) void k_down3(
    const float* __restrict__ x, const float* __restrict__ Wtg,
    unsigned short* __restrict__ xdp, float* __restrict__ st /*96*/)
{
    __shared__ float bins[96];
    const int tid = threadIdx.x;
    if (tid < 96) bins[tid] = 0.f;
    __syncthreads();

    const int base = (blockIdx.x * 256 + tid) * 2;
    const int n = base / 3200, pb = base - n * 3200;
    const float* xb = x + n * 204800 + pb;

    float acc0[48], acc1[48];
#pragma unroll
    for (int k = 0; k < 48; k++) { acc0[k] = 0.f; acc1[k] = 0.f; }

    for (int c = 0; c < 64; c++) {
        float2 xv = *(const float2*)&xb[c * 3200];
        const float4* wr = (const float4*)(Wtg + c * 48);   // uniform -> s_load
#pragma unroll
        for (int q = 0; q < 12; q++) {
            float4 w = wr[q];
            acc0[4*q+0] += w.x * xv.x;  acc1[4*q+0] += w.x * xv.y;
            acc0[4*q+1] += w.y * xv.x;  acc1[4*q+1] += w.y * xv.y;
            acc0[4*q+2] += w.z * xv.x;  acc1[4*q+2] += w.z * xv.y;
            acc0[4*q+3] += w.w * xv.x;  acc1[4*q+3] += w.w * xv.y;
        }
    }
#pragma unroll
    for (int l = 0; l < 3; l++) {
        unsigned int pk0[8], pk1[8];
#pragma unroll
        for (int h = 0; h < 8; h++) {
            pk0[h] = packbf(acc0[l*16 + 2*h], acc0[l*16 + 2*h + 1]);
            pk1[h] = packbf(acc1[l*16 + 2*h], acc1[l*16 + 2*h + 1]);
        }
        uint4* dst = (uint4*)(xdp + (size_t)l * XDP_ELEMS + (size_t)base * 16);
        dst[0] = make_uint4(pk0[0], pk0[1], pk0[2], pk0[3]);
        dst[1] = make_uint4(pk0[4], pk0[5], pk0[6], pk0[7]);
        dst[2] = make_uint4(pk1[0], pk1[1], pk1[2], pk1[3]);
        dst[3] = make_uint4(pk1[4], pk1[5], pk1[6], pk1[7]);
    }

    const int lane = tid & 63;
#pragma unroll
    for (int k = 0; k < 48; k++) {
        float sv = wave_sum(acc0[k] + acc1[k]);
        float qv = wave_sum(acc0[k] * acc0[k] + acc1[k] * acc1[k]);
        if (lane == 0) { atomicAdd(&bins[k], sv); atomicAdd(&bins[48 + k], qv); }
    }
    __syncthreads();
    if (tid < 96) atomicAdd(&st[tid], bins[tid]);
}

// ---- K2: finalize down affines
__global__ __launch_bounds__(64) void k_findown(
    const float* __restrict__ st, const float* __restrict__ gd,
    const float* __restrict__ betad, float* __restrict__ AC)
{
    int t = threadIdx.x;
    if (t < 48) {
        float m   = st[t] * (1.f / CNTF);
        float var = st[48 + t] * (1.f / CNTF) - m * m;
        float a   = gd[t] * rsqrtf(var + EPS);
        AC[t]      = a;
        AC[48 + t] = betad[t] - a * m;
    }
}

// ---- K3: ALL-layer z stats via MFMA (fused; layer = blockIdx>>9).
// PA fragments in LDS (saves 40 VGPR -> fits 128 cap WITHOUT spill);
// 8 nt per wave; (256,2) -> 2 blocks/CU.
__global__ __launch_bounds__(256, 2) void k_zstats3(
    const unsigned short* __restrict__ xdp,  // [3][nt][u<25][16c] bf16
    const float* __restrict__ PA,            // [3][5][25][25]
    const float* __restrict__ Wsub,          // [3][80][16]
    const float* __restrict__ AC,            // [96]
    float* __restrict__ stq)                 // [3][160]
{
    __shared__ unsigned int PAfr[10 * 64 * 4];   // 10 frags x 64 lanes x uint4
    __shared__ unsigned short xtile[4][512];
    __shared__ float bins[160];

    const int l   = blockIdx.x >> 9;
    const int blk = blockIdx.x & 511;
    const unsigned short* xd = xdp + (size_t)l * XDP_ELEMS;
    const float* PAl = PA + l * 3125;
    const float* Wsl = Wsub + l * 1280;

    const int tid  = threadIdx.x;
    const int wave = tid >> 6, lane = tid & 63;
    const int lr = lane & 15, lg = lane >> 4;

    // build PA fragments in LDS (10 frags: [s][t])
    for (int e = tid; e < 640; e += 256) {
        int frag = e >> 6, ln = e & 63;
        int s = frag >> 1, t = frag & 1;
        int elr = ln & 15, elg = ln >> 4;
        int v = t * 16 + elr;
        unsigned int u4[4];
#pragma unroll
        for (int h = 0; h < 4; h++) {
            int u0 = 8 * h + elg, u1 = 8 * h + 4 + elg;
            float f0 = (v < 25 && u0 < 25) ? PAl[(s * 25 + v) * 25 + u0] : 0.f;
            float f1 = (v < 25 && u1 < 25) ? PAl[(s * 25 + v) * 25 + u1] : 0.f;
            u4[h] = packbf(f0, f1);
        }
        *(uint4*)&PAfr[e * 4] = make_uint4(u4[0], u4[1], u4[2], u4[3]);
    }
    *(uint4*)&xtile[tid >> 6][(tid & 63) * 8] = make_uint4(0, 0, 0, 0);
    for (int i = tid; i < 160; i += 256) bins[i] = 0.f;

    // GEMM2 A-operand (W): elem r<4 = W[o=lr][c=4*lg+r], elems 4..7 = 0
    bf16x8 Wfrag[5];
#pragma unroll
    for (int s = 0; s < 5; s++) {
        FRAG f;
        const float* wr = Wsl + (s * 16 + lr) * 16 + 4 * lg;
        f.u[0] = packbf(wr[0], wr[1]);
        f.u[1] = packbf(wr[2], wr[3]);
        f.u[2] = 0u; f.u[3] = 0u;
        Wfrag[s] = f.v;
    }

    const float a_c = AC[l * 16 + lr], c_c = AC[48 + l * 16 + lr];

    f32x4 sacc[5] = {};
    f32x4 qacc[5] = {};
    const f32x4 zero = {};
    __syncthreads();   // PAfr + xtile zeros visible

    const int wid = blk * 4 + wave;
    const unsigned short* sbase = xd + lane * 8;   // + nt*400
    unsigned short* dstp = &xtile[wave][lane * 8];
    uint4 pre = make_uint4(0, 0, 0, 0);
    if (lane < 50) pre = *(const uint4*)(sbase + (size_t)(wid * 8) * 400);

    for (int k = 0; k < 8; k++) {
        if (lane < 50) *(uint4*)dstp = pre;
        if (k < 7 && lane < 50)
            pre = *(const uint4*)(sbase + (size_t)(wid * 8 + k + 1) * 400);
        asm volatile("s_waitcnt lgkmcnt(0)" ::: "memory");
        __builtin_amdgcn_sched_barrier(0);

        FRAG af;
#pragma unroll
        for (int h = 0; h < 4; h++) {
            int u0 = 8 * h + lg, u1 = 8 * h + 4 + lg;
            float x0 = bfu(xtile[wave][u0 * 16 + lr]);
            float x1 = bfu(xtile[wave][u1 * 16 + lr]);
            x0 = fmaxf(a_c * x0 + c_c, 0.f);
            x1 = fmaxf(a_c * x1 + c_c, 0.f);
            af.u[h] = packbf(x0, x1);
        }
        const bf16x8 A = af.v;

#pragma unroll
        for (int s = 0; s < 5; s++) {
            FRAG bfA, bfB;
            *(uint4*)bfA.u = *(const uint4*)&PAfr[((s * 2 + 0) * 64 + lane) * 4];
            *(uint4*)bfB.u = *(const uint4*)&PAfr[((s * 2 + 1) * 64 + lane) * 4];
            f32x4 d0 = __builtin_amdgcn_mfma_f32_16x16x32_bf16(A, bfA.v, zero, 0, 0, 0);
            f32x4 d1 = __builtin_amdgcn_mfma_f32_16x16x32_bf16(A, bfB.v, zero, 0, 0, 0);
            f32x4 z0 = __builtin_amdgcn_mfma_f32_16x16x32_bf16(Wfrag[s], packD(d0), zero, 0, 0, 0);
            f32x4 z1 = __builtin_amdgcn_mfma_f32_16x16x32_bf16(Wfrag[s], packD(d1), zero, 0, 0, 0);
            sacc[s] += z0; qacc[s] += z0 * z0;
            if (lr < 9) { sacc[s] += z1; qacc[s] += z1 * z1; }
        }
    }

#pragma unroll
    for (int s = 0; s < 5; s++)
#pragma unroll
        for (int r = 0; r < 4; r++) {
            float sv = sacc[s][r], qv = qacc[s][r];
            sv += __shfl_xor(sv, 1, 64); qv += __shfl_xor(qv, 1, 64);
            sv += __shfl_xor(sv, 2, 64); qv += __shfl_xor(qv, 2, 64);
            sv += __shfl_xor(sv, 4, 64); qv += __shfl_xor(qv, 4, 64);
            sv += __shfl_xor(sv, 8, 64); qv += __shfl_xor(qv, 8, 64);
            if (lr == 0) {
                atomicAdd(&bins[s * 16 + 4 * lg + r], sv);
                atomicAdd(&bins[80 + s * 16 + 4 * lg + r], qv);
            }
        }
    __syncthreads();
    for (int i = tid; i < 160; i += 256) atomicAdd(&stq[l * 160 + i], bins[i]);
}

// ---- K4: fold sub-BN affine into W (W2 = A*W, bf16) and constants into Cagg[64]
__global__ __launch_bounds__(256) void k_finsub(
    const float* __restrict__ stq,    // [3][160]
    const float* __restrict__ Wsub,   // [3][80][16]
    const float* __restrict__ gs, const float* __restrict__ betas,
    unsigned short* __restrict__ W2,  // [3][80][16] bf16 (A-scaled)
    float* __restrict__ Cagg)         // [64]
{
    __shared__ float As[240], Cs[240];
    const int tid = threadIdx.x;
    if (tid < 240) {
        int l = tid / 80, ch = tid - l * 80;
        float m   = stq[l * 160 + ch] * (1.f / CNTF);
        float var = stq[l * 160 + 80 + ch] * (1.f / CNTF) - m * m;
        float a   = gs[l * 80 + ch] * rsqrtf(var + EPS);
        As[tid] = a;
        Cs[tid] = betas[l * 80 + ch] - a * m;
    }
    __syncthreads();
    for (int i = tid; i < 3840; i += 256) {
        int l = i / 1280, r = i - l * 1280, ch = r / 16;
        W2[i] = f2bfu(As[l * 80 + ch] * Wsub[i]);
    }
    if (tid < 64) {
        int sIdx = tid >> 4, o = tid & 15;
        float c = 0.f;
        for (int l = 0; l < 3; l++)
            c += Cs[l * 80 + (sIdx + 1) * 16 + o] + Cs[l * 80 + o];
        Cagg[tid] = c;
    }
}

// ---- K5: fused 3-layer output via MFMA -> bf16 acc [nt][v][64] + final-BN stats.
__global__ __launch_bounds__(256, 1) void k_out_mfma(
    const unsigned short* __restrict__ xdp,  // [3][nt][u<25][16c]
    const float* __restrict__ PA,            // [3][5][25][25]
    const unsigned short* __restrict__ W2,   // [3][80][16] bf16
    const float* __restrict__ Cagg,          // [64]
    const float* __restrict__ AC,            // [96] down affines
    float* __restrict__ stout,               // [128]
    unsigned short* __restrict__ accb)       // [nt][25][64] bf16
{
    __shared__ unsigned int PAfr[30 * 64 * 4];     // 30 frags x 64 lanes x uint4
    __shared__ unsigned short xtile[4][3][512];
    __shared__ float bins[128];

    const int tid  = threadIdx.x;
    const int wave = tid >> 6, lane = tid & 63;
    const int lr = lane & 15, lg = lane >> 4;

    for (int e = tid; e < 1920; e += 256) {
        int frag = e >> 6, ln = e & 63;
        int l = frag / 10, rem = frag - l * 10;
        int s = rem >> 1, t = rem & 1;
        int elr = ln & 15, elg = ln >> 4;
        int v = t * 16 + elr;
        unsigned int u4[4];
#pragma unroll
        for (int h = 0; h < 4; h++) {
            int u0 = 8 * h + elg, u1 = 8 * h + 4 + elg;
            float f0 = (v < 25 && u0 < 25) ? PA[l * 3125 + (s * 25 + v) * 25 + u0] : 0.f;
            float f1 = (v < 25 && u1 < 25) ? PA[l * 3125 + (s * 25 + v) * 25 + u1] : 0.f;
            u4[h] = packbf(f0, f1);
        }
        *(uint4*)&PAfr[e * 4] = make_uint4(u4[0], u4[1], u4[2], u4[3]);
    }
    for (int i = tid; i < 768; i += 256)
        *(uint4*)&xtile[0][0][i * 8] = make_uint4(0, 0, 0, 0);
    if (tid < 128) bins[tid] = 0.f;

    // GEMM2 A-operand (pre-scaled W): elem r<4 = W2[o=lr][4*lg+r], rest 0
    bf16x8 Wf[3][5];
#pragma unroll
    for (int l = 0; l < 3; l++)
#pragma unroll
        for (int s = 0; s < 5; s++) {
            FRAG f;
            const uint2 w = *(const uint2*)(W2 + ((l * 5 + s) * 16 + lr) * 16 + 4 * lg);
            f.u[0] = w.x; f.u[1] = w.y; f.u[2] = 0u; f.u[3] = 0u;
            Wf[l][s] = f.v;
        }

    float a3[3], c3[3];
#pragma unroll
    for (int l = 0; l < 3; l++) { a3[l] = AC[l * 16 + lr]; c3[l] = AC[48 + l * 16 + lr]; }

    float cagg[4][4];
#pragma unroll
    for (int sI = 0; sI < 4; sI++)
#pragma unroll
        for (int r = 0; r < 4; r++) cagg[sI][r] = Cagg[sI * 16 + 4 * lg + r];

    f32x4 ss[4] = {}, qq[4] = {};
    const f32x4 zero = {};
    __syncthreads();   // PAfr + xtile zero-init visible to all waves

    const int wid = blockIdx.x * 4 + wave;

    // per-lane staging geometry (loop-invariant)
    const int j0 = lane,       l0 = j0 / 50, o0 = j0 - l0 * 50;
    const int j1 = lane + 64,  l1 = j1 / 50, o1 = j1 - l1 * 50;
    const int j2 = lane + 128, l2 = j2 / 50, o2 = j2 - l2 * 50;
    const bool a2 = (j2 < 150);
    const unsigned short* s0 = xdp + (size_t)l0 * XDP_ELEMS + o0 * 8;
    const unsigned short* s1 = xdp + (size_t)l1 * XDP_ELEMS + o1 * 8;
    const unsigned short* s2 = xdp + (size_t)l2 * XDP_ELEMS + o2 * 8;
    unsigned short* d0 = &xtile[wave][l0][o0 * 8];
    unsigned short* d1 = &xtile[wave][l1][o1 * 8];
    unsigned short* d2 = &xtile[wave][l2][o2 * 8];

    uint4 pre0, pre1, pre2 = make_uint4(0, 0, 0, 0);
    {
        size_t b = (size_t)(wid * 4) * 400;
        pre0 = *(const uint4*)(s0 + b);
        pre1 = *(const uint4*)(s1 + b);
        if (a2) pre2 = *(const uint4*)(s2 + b);
    }

    for (int k = 0; k < 4; k++) {
        const int nt = wid * 4 + k;
        *(uint4*)d0 = pre0;
        *(uint4*)d1 = pre1;
        if (a2) *(uint4*)d2 = pre2;
        if (k < 3) {
            size_t b = (size_t)(nt + 1) * 400;
            pre0 = *(const uint4*)(s0 + b);
            pre1 = *(const uint4*)(s1 + b);
            if (a2) pre2 = *(const uint4*)(s2 + b);
        }
        asm volatile("s_waitcnt lgkmcnt(0)" ::: "memory");
        __builtin_amdgcn_sched_barrier(0);

        f32x4 acc0[4] = {}, acc1[4] = {};
#pragma unroll
        for (int l = 0; l < 3; l++) {
            FRAG af;
#pragma unroll
            for (int h = 0; h < 4; h++) {
                int u0 = 8 * h + lg, u1 = 8 * h + 4 + lg;
                float x0 = bfu(xtile[wave][l][u0 * 16 + lr]);
                float x1 = bfu(xtile[wave][l][u1 * 16 + lr]);
                x0 = fmaxf(a3[l] * x0 + c3[l], 0.f);
                x1 = fmaxf(a3[l] * x1 + c3[l], 0.f);
                af.u[h] = packbf(x0, x1);
            }
            const bf16x8 A = af.v;

            f32x4 z0a, z0b;
#pragma unroll
            for (int s = 0; s < 5; s++) {
                FRAG bfA, bfB;
                *(uint4*)bfA.u = *(const uint4*)&PAfr[(((l * 5 + s) * 2 + 0) * 64 + lane) * 4];
                *(uint4*)bfB.u = *(const uint4*)&PAfr[(((l * 5 + s) * 2 + 1) * 64 + lane) * 4];
                f32x4 dA = __builtin_amdgcn_mfma_f32_16x16x32_bf16(A, bfA.v, zero, 0, 0, 0);
                f32x4 dB = __builtin_amdgcn_mfma_f32_16x16x32_bf16(A, bfB.v, zero, 0, 0, 0);
                f32x4 za = __builtin_amdgcn_mfma_f32_16x16x32_bf16(Wf[l][s], packD(dA), zero, 0, 0, 0);
                f32x4 zb = __builtin_amdgcn_mfma_f32_16x16x32_bf16(Wf[l][s], packD(dB), zero, 0, 0, 0);
                if (s == 0) { z0a = za; z0b = zb; }
                else {
                    acc0[s - 1] += za + z0a;
                    acc1[s - 1] += zb + z0b;
                }
            }
        }

        // bf16 acc write: [nt][v][64ch]; each (nt,v) row = 128B line.
        unsigned short* ab0 = accb + ((size_t)nt * 25 + lr) * 64;
        unsigned short* ab1 = accb + ((size_t)nt * 25 + 16 + lr) * 64;
#pragma unroll
        for (int sI = 0; sI < 4; sI++) {
            float v00 = acc0[sI][0] + cagg[sI][0];
            float v01 = acc0[sI][1] + cagg[sI][1];
            float v02 = acc0[sI][2] + cagg[sI][2];
            float v03 = acc0[sI][3] + cagg[sI][3];
            *(uint2*)(ab0 + sI * 16 + 4 * lg) =
                make_uint2(packbf(v00, v01), packbf(v02, v03));
            float v10 = acc1[sI][0] + cagg[sI][0];
            float v11 = acc1[sI][1] + cagg[sI][1];
            float v12 = acc1[sI][2] + cagg[sI][2];
            float v13 = acc1[sI][3] + cagg[sI][3];
            float u0 = (lr < 9) ? v10 : 0.f, u1 = (lr < 9) ? v11 : 0.f;
            float u2 = (lr < 9) ? v12 : 0.f, u3 = (lr < 9) ? v13 : 0.f;
            if (lr < 9)
                *(uint2*)(ab1 + sI * 16 + 4 * lg) =
                    make_uint2(packbf(v10, v11), packbf(v12, v13));
            ss[sI][0] += v00 + u0; qq[sI][0] += v00 * v00 + u0 * u0;
            ss[sI][1] += v01 + u1; qq[sI][1] += v01 * v01 + u1 * u1;
            ss[sI][2] += v02 + u2; qq[sI][2] += v02 * v02 + u2 * u2;
            ss[sI][3] += v03 + u3; qq[sI][3] += v03 * v03 + u3 * u3;
        }
    }

#pragma unroll
    for (int sI = 0; sI < 4; sI++)
#pragma unroll
        for (int r = 0; r < 4; r++) {
            float sv = ss[sI][r], qv = qq[sI][r];
            sv += __shfl_xor(sv, 1, 64); qv += __shfl_xor(qv, 1, 64);
            sv += __shfl_xor(sv, 2, 64); qv += __shfl_xor(qv, 2, 64);
            sv += __shfl_xor(sv, 4, 64); qv += __shfl_xor(qv, 4, 64);
            sv += __shfl_xor(sv, 8, 64); qv += __shfl_xor(qv, 8, 64);
            if (lr == 0) {
                atomicAdd(&bins[sI * 16 + 4 * lg + r], sv);
                atomicAdd(&bins[64 + sI * 16 + 4 * lg + r], qv);
            }
        }
    __syncthreads();
    if (tid < 128) atomicAdd(&stout[tid], bins[tid]);
}

// ---- K6: out = relu(bn(acc) + x), coalesced via LDS transpose (8 nt/block)
__global__ __launch_bounds__(256, 2) void k_final2(
    const unsigned short* __restrict__ accb, const float* __restrict__ x,
    const float* __restrict__ go, const float* __restrict__ bo,
    const float* __restrict__ stout, float* __restrict__ out)
{
    __shared__ float ao[64], co[64];
    __shared__ float tile[32][208];
    const int tid = threadIdx.x;
    if (tid < 64) {
        float m   = stout[tid] * (1.f / CNTF);
        float var = stout[64 + tid] * (1.f / CNTF) - m * m;
        float a   = go[tid] * rsqrtf(var + EPS);
        ao[tid] = a; co[tid] = bo[tid] - m * a;
    }

    const int nt0 = blockIdx.x * 8, n = nt0 >> 7, t0 = nt0 & 127;
    const int pp = tid / 25, v = tid - pp * 25;
    const unsigned short* arow = accb + ((size_t)(nt0 + pp) * 25 + v) * 64;

#pragma unroll
    for (int h = 0; h < 2; h++) {
        __syncthreads();   // ao/co ready (h=0) / prev-half tile reads done (h=1)
        if (tid < 200) {
#pragma unroll
            for (int j = 0; j < 4; j++) {
                uint4 w = *(const uint4*)(arow + h * 32 + j * 8);
                const int cb = h * 32 + j * 8;
                tile[j*8+0][tid] = ao[cb+0] * bfu(w.x & 0xffffu) + co[cb+0];
                tile[j*8+1][tid] = ao[cb+1] * bfu(w.x >> 16)     + co[cb+1];
                tile[j*8+2][tid] = ao[cb+2] * bfu(w.y & 0xffffu) + co[cb+2];
                tile[j*8+3][tid] = ao[cb+3] * bfu(w.y >> 16)     + co[cb+3];
                tile[j*8+4][tid] = ao[cb+4] * bfu(w.z & 0xffffu) + co[cb+4];
                tile[j*8+5][tid] = ao[cb+5] * bfu(w.z >> 16)     + co[cb+5];
                tile[j*8+6][tid] = ao[cb+6] * bfu(w.w & 0xffffu) + co[cb+6];
                tile[j*8+7][tid] = ao[cb+7] * bfu(w.w >> 16)     + co[cb+7];
            }
        }
        __syncthreads();
        for (int i = tid; i < 6400; i += 256) {
            int kk = i / 200, p = i - kk * 200;
            int adr = n * 204800 + (h * 32 + kk) * 3200 + t0 * 25 + p;
            out[adr] = fmaxf(tile[kk][p] + x[adr], 0.f);
        }
    }
}

extern "C" void kernel_launch(void* const* d_in, const int* in_sizes, int n_in,
                              void* d_out, int out_size, void* d_ws, size_t ws_size,
                              hipStream_t stream)
{
    const float* x     = (const float*)d_in[0];
    const float* PA    = (const float*)d_in[1];
    const float* Wd    = (const float*)d_in[2];
    const float* gd    = (const float*)d_in[4];
    const float* betad = (const float*)d_in[5];
    const float* Wsub  = (const float*)d_in[6];
    const float* gsub  = (const float*)d_in[8];
    const float* betas = (const float*)d_in[9];
    const float* gout  = (const float*)d_in[10];
    const float* betao = (const float*)d_in[11];
    float* out = (float*)d_out;

    unsigned short* xdp  = (unsigned short*)d_ws;            // 39.3 MB
    unsigned short* accb = xdp + (size_t)3 * XDP_ELEMS;      // 52.4 MB bf16
    float* st    = (float*)(accb + (size_t)ACC_ELEMS);
    float* AC    = st + 96;
    float* stq   = AC + 96;       // [3][160]
    float* stout = stq + 480;     // [128]
    float* Wtg   = stout + 128;   // [64][48]
    float* Cagg  = Wtg + 3072;    // [64]
    unsigned short* W2 = (unsigned short*)(Cagg + 64);  // [3][80][16] bf16

    hipMemsetAsync(st, 0, (96 + 96 + 480 + 128) * sizeof(float), stream);

    k_prep   <<<1,   256, 0, stream>>>(Wd, Wtg);
    k_down3  <<<800, 256, 0, stream>>>(x, Wtg, xdp, st);
    k_findown<<<1,    64, 0, stream>>>(st, gd, betad, AC);

    k_zstats3 <<<1536, 256, 0, stream>>>(xdp, PA, Wsub, AC, stq);
    k_finsub  <<<1,    256, 0, stream>>>(stq, Wsub, gsub, betas, W2, Cagg);
    k_out_mfma<<<1024, 256, 0, stream>>>(xdp, PA, W2, Cagg, AC, stout, accb);
    k_final2  <<<2048, 256, 0, stream>>>(accb, x, gout, betao, stout, out);
}